// Round 1
// baseline (366.441 us; speedup 1.0000x reference)
//
#include <hip/hip_runtime.h>
#include <hip/hip_bf16.h>
#include <cstdint>
#include <cstddef>

// ---------------- problem constants ----------------
#define E    512
#define H    8
#define DHD  64
#define FDIM 2048
#define KS   33
#define BB   2
#define LL   4096
#define LP1  4097
#define NTOK 8194   // BB*LP1
#define NLOC 8192   // BB*LL

typedef unsigned short ushort_t;
typedef __bf16 bf16x8_t __attribute__((ext_vector_type(8)));
typedef float  f32x4_t  __attribute__((ext_vector_type(4)));

__device__ __forceinline__ float b2f(unsigned short h) {
  union { unsigned int u; float f; } un; un.u = ((unsigned int)h) << 16; return un.f;
}
__device__ __forceinline__ unsigned short f2b(float f) {
  union { float f; unsigned int u; } un; un.f = f;
  unsigned int u = un.u;
  return (unsigned short)((u + 0x7FFFu + ((u >> 16) & 1u)) >> 16);
}

__device__ __forceinline__ void gload16(const ushort_t* g, ushort_t* l) {
  __builtin_amdgcn_global_load_lds(
      (const __attribute__((address_space(1))) void*)g,
      (__attribute__((address_space(3))) void*)l,
      16, 0, 0);
}

// ---------------- bf16 MFMA GEMM:  C = A(MxK) @ W(NxK)^T + bias ----------------
// m97 structure: 128x128 tile, BK=32, 4 waves (2x2), global_load_lds w=16,
// 2-barrier K-loop.  16x16x32 bf16 MFMA; A and B fragment loads are symmetric
// because both operands are K-contiguous (A @ W^T).
#define BM 128
#define BN 128
#define BK 32

template<int ACT, int OUTF, int ADDRES, int INRM, int OUTRM>
__global__ __launch_bounds__(256) void gemm_bt(
    const ushort_t* __restrict__ A, const ushort_t* __restrict__ W,
    const float* __restrict__ bias, float* __restrict__ outF,
    ushort_t* __restrict__ outB, const float* __restrict__ res,
    int M, int N, int K)
{
  __shared__ ushort_t Alds[BM * BK];
  __shared__ ushort_t Blds[BN * BK];
  const int t    = threadIdx.x;
  const int lane = t & 63;
  const int w    = t >> 6;
  const int wr   = w >> 1, wc = w & 1;
  const int bmBase = blockIdx.x * BM;
  const int bnBase = blockIdx.y * BN;

  f32x4_t zero = {0.f, 0.f, 0.f, 0.f};
  f32x4_t acc[4][4];
  #pragma unroll
  for (int m = 0; m < 4; ++m)
    #pragma unroll
    for (int n = 0; n < 4; ++n) acc[m][n] = zero;

  // staging: chunk c = i*256+t, 16B each; LDS linear row-major [row][k]
  int r0 = bmBase + (t >> 2);
  int r1 = r0 + 64;
  if (INRM) { r0 += r0 >> 12; r1 += r1 >> 12; }          // local-row -> padded-row
  else      { if (r0 >= M) r0 = M - 1; if (r1 >= M) r1 = M - 1; }
  const int ako = (t & 3) * 8;
  const int n0  = bnBase + (t >> 2);
  const int n1  = n0 + 64;

  const int frow = lane & 15;          // fragment row (m-index / n-index)
  const int fk   = (lane >> 4) * 8;    // fragment k offset

  for (int k0 = 0; k0 < K; k0 += BK) {
    gload16(A + (size_t)r0 * K + k0 + ako, &Alds[(size_t)t * 8]);
    gload16(A + (size_t)r1 * K + k0 + ako, &Alds[(size_t)(256 + t) * 8]);
    gload16(W + (size_t)n0 * K + k0 + ako, &Blds[(size_t)t * 8]);
    gload16(W + (size_t)n1 * K + k0 + ako, &Blds[(size_t)(256 + t) * 8]);
    __syncthreads();   // vmcnt(0) drain -> tiles ready
    bf16x8_t af[4], bf[4];
    #pragma unroll
    for (int m = 0; m < 4; ++m)
      af[m] = *reinterpret_cast<const bf16x8_t*>(&Alds[(wr * 64 + m * 16 + frow) * BK + fk]);
    #pragma unroll
    for (int n = 0; n < 4; ++n)
      bf[n] = *reinterpret_cast<const bf16x8_t*>(&Blds[(wc * 64 + n * 16 + frow) * BK + fk]);
    #pragma unroll
    for (int m = 0; m < 4; ++m)
      #pragma unroll
      for (int n = 0; n < 4; ++n)
        acc[m][n] = __builtin_amdgcn_mfma_f32_16x16x32_bf16(af[m], bf[n], acc[m][n], 0, 0, 0);
    __syncthreads();   // protect LDS before next stage
  }

  // epilogue: C/D layout col=lane&15, row=(lane>>4)*4+r  (m89-verified)
  const int rbase = (lane >> 4) * 4;
  const int cbase = lane & 15;
  #pragma unroll
  for (int m = 0; m < 4; ++m) {
    #pragma unroll
    for (int r = 0; r < 4; ++r) {
      int gr = bmBase + wr * 64 + m * 16 + rbase + r;
      if (gr < M) {
        int orow = OUTRM ? gr + (gr >> 12) : gr;
        #pragma unroll
        for (int n = 0; n < 4; ++n) {
          int gc = bnBase + wc * 64 + n * 16 + cbase;
          float v = acc[m][n][r] + bias[gc];
          if (ACT == 1) v = v / (1.f + __expf(-v));       // SiLU
          if (ADDRES) v += res[(size_t)gr * N + gc];
          if (OUTF) outF[(size_t)orow * N + gc] = v;
          else      outB[(size_t)orow * N + gc] = f2b(v);
        }
      }
    }
  }
}

// ---------------- LN1 (also copies cls rows into tmp_key) ----------------
__global__ __launch_bounds__(256) void ln_fused1(
    const float* __restrict__ x, const float* __restrict__ g,
    const float* __restrict__ be, ushort_t* __restrict__ xn,
    ushort_t* __restrict__ tmpk)
{
  __shared__ float sh[4];
  const int row = blockIdx.x;
  const int t = threadIdx.x;
  const float* xr = x + (size_t)row * E;
  float v0 = xr[t], v1 = xr[t + 256];
  float sum = v0 + v1;
  #pragma unroll
  for (int o = 32; o; o >>= 1) sum += __shfl_xor(sum, o);
  if ((t & 63) == 0) sh[t >> 6] = sum;
  __syncthreads();
  float mean = (sh[0] + sh[1] + sh[2] + sh[3]) * (1.f / E);
  __syncthreads();
  float d0 = v0 - mean, d1 = v1 - mean;
  float vs = d0 * d0 + d1 * d1;
  #pragma unroll
  for (int o = 32; o; o >>= 1) vs += __shfl_xor(vs, o);
  if ((t & 63) == 0) sh[t >> 6] = vs;
  __syncthreads();
  float var = (sh[0] + sh[1] + sh[2] + sh[3]) * (1.f / E);
  float rstd = rsqrtf(var + 1e-5f);
  unsigned short o0 = f2b(d0 * rstd * g[t] + be[t]);
  unsigned short o1 = f2b(d1 * rstd * g[t + 256] + be[t + 256]);
  xn[(size_t)row * E + t] = o0;
  xn[(size_t)row * E + t + 256] = o1;
  if ((row % LP1) == LL) {  // cls rows -> tmp_key rows 4096 / 8193
    tmpk[(size_t)row * E + t] = o0;
    tmpk[(size_t)row * E + t + 256] = o1;
  }
}

// ---------------- residual-add + LN2 ----------------
__global__ __launch_bounds__(256) void resid_ln2(
    const float* __restrict__ x, const ushort_t* __restrict__ tmpk,
    const float* __restrict__ xcls, const float* __restrict__ g,
    const float* __restrict__ be, float* __restrict__ xa,
    ushort_t* __restrict__ xn2)
{
  __shared__ float sh[4];
  const int row = blockIdx.x;
  const int b = row / LP1, l = row % LP1;
  const int t = threadIdx.x;
  float a0, a1;
  if (l < LL) { a0 = b2f(tmpk[(size_t)row * E + t]); a1 = b2f(tmpk[(size_t)row * E + t + 256]); }
  else        { a0 = xcls[b * E + t];                a1 = xcls[b * E + t + 256]; }
  float v0 = x[(size_t)row * E + t] + a0;
  float v1 = x[(size_t)row * E + t + 256] + a1;
  xa[(size_t)row * E + t] = v0;
  xa[(size_t)row * E + t + 256] = v1;
  float sum = v0 + v1;
  #pragma unroll
  for (int o = 32; o; o >>= 1) sum += __shfl_xor(sum, o);
  if ((t & 63) == 0) sh[t >> 6] = sum;
  __syncthreads();
  float mean = (sh[0] + sh[1] + sh[2] + sh[3]) * (1.f / E);
  __syncthreads();
  float d0 = v0 - mean, d1 = v1 - mean;
  float vs = d0 * d0 + d1 * d1;
  #pragma unroll
  for (int o = 32; o; o >>= 1) vs += __shfl_xor(vs, o);
  if ((t & 63) == 0) sh[t >> 6] = vs;
  __syncthreads();
  float var = (sh[0] + sh[1] + sh[2] + sh[3]) * (1.f / E);
  float rstd = rsqrtf(var + 1e-5f);
  xn2[(size_t)row * E + t]       = f2b(d0 * rstd * g[t] + be[t]);
  xn2[(size_t)row * E + t + 256] = f2b(d1 * rstd * g[t + 256] + be[t + 256]);
}

// ---------------- neighborhood attention: wave per (b,l,h) ----------------
__global__ __launch_bounds__(256) void natten_kernel(
    const ushort_t* __restrict__ qkv, ushort_t* __restrict__ out)
{
  __shared__ float qsh[4][64];
  __shared__ float psh[4][64];
  const int w    = threadIdx.x >> 6;
  const int lane = threadIdx.x & 63;
  const int task = blockIdx.x * 4 + w;
  const int h = task & 7;
  const int l = (task >> 3) & (LL - 1);
  const int b = task >> 15;
  int start = l - 16;
  start = start < 0 ? 0 : (start > LL - KS ? LL - KS : start);
  const ushort_t* base = qkv + (size_t)b * LL * (3 * E);
  qsh[w][lane] = b2f(base[(size_t)l * (3 * E) + h * 64 + lane]) * 0.125f;
  __syncthreads();
  float s = -1e30f;
  if (lane < KS) {
    const ushort_t* krow = base + (size_t)(start + lane) * (3 * E) + E + h * 64;
    float a = 0.f;
    #pragma unroll
    for (int d0 = 0; d0 < 64; d0 += 4) {
      ushort4 kv = *reinterpret_cast<const ushort4*>(krow + d0);
      a += qsh[w][d0]     * b2f(kv.x);
      a += qsh[w][d0 + 1] * b2f(kv.y);
      a += qsh[w][d0 + 2] * b2f(kv.z);
      a += qsh[w][d0 + 3] * b2f(kv.w);
    }
    s = a;
  }
  float mx = s;
  #pragma unroll
  for (int o = 32; o; o >>= 1) mx = fmaxf(mx, __shfl_xor(mx, o));
  float p = (lane < KS) ? __expf(s - mx) : 0.f;
  float sum = p;
  #pragma unroll
  for (int o = 32; o; o >>= 1) sum += __shfl_xor(sum, o);
  p /= sum;
  psh[w][lane] = p;
  __syncthreads();
  const ushort_t* vcol = base + 2 * E + h * 64 + lane;
  float o = 0.f;
  for (int j = 0; j < KS; ++j)
    o += psh[w][j] * b2f(vcol[(size_t)(start + j) * (3 * E)]);
  out[((size_t)(b * LL) + l) * E + h * 64 + lane] = f2b(o);
}

// ---------------- global MHA pieces (CLS query) ----------------
__global__ __launch_bounds__(256) void qcls_kernel(
    const ushort_t* __restrict__ xn, const float* __restrict__ inw,
    const float* __restrict__ inb, float* __restrict__ qcls)
{
  int i = blockIdx.x * 256 + threadIdx.x;   // 0..1023
  int b = i >> 9, d = i & 511;
  const ushort_t* xr = xn + ((size_t)b * LP1 + LL) * E;
  const float* wr = inw + (size_t)d * E;
  float s = 0.f;
  for (int e = 0; e < E; e += 4) {
    ushort4 xv = *reinterpret_cast<const ushort4*>(xr + e);
    s += b2f(xv.x) * wr[e] + b2f(xv.y) * wr[e + 1] + b2f(xv.z) * wr[e + 2] + b2f(xv.w) * wr[e + 3];
  }
  qcls[i] = (s + inb[d]) * 0.125f;
}

__global__ __launch_bounds__(256) void gscore_kernel(
    const float* __restrict__ qcls, const ushort_t* __restrict__ kg,
    float* __restrict__ sc)
{
  const int wav = blockIdx.x * 4 + (threadIdx.x >> 6);
  if (wav >= BB * LP1) return;
  const int lane = threadIdx.x & 63;
  const int b = wav / LP1, j = wav % LP1;
  const ushort_t* kr = kg + (size_t)wav * E + lane * 8;
  const float* q = qcls + b * E + lane * 8;
  ushort4 ka = *reinterpret_cast<const ushort4*>(kr);
  ushort4 kb = *reinterpret_cast<const ushort4*>(kr + 4);
  float s = b2f(ka.x) * q[0] + b2f(ka.y) * q[1] + b2f(ka.z) * q[2] + b2f(ka.w) * q[3]
          + b2f(kb.x) * q[4] + b2f(kb.y) * q[5] + b2f(kb.z) * q[6] + b2f(kb.w) * q[7];
  s += __shfl_xor(s, 1); s += __shfl_xor(s, 2); s += __shfl_xor(s, 4);
  if ((lane & 7) == 0) sc[((size_t)(b * 8) + (lane >> 3)) * LP1 + j] = s;
}

__global__ __launch_bounds__(256) void gsoftmax_kernel(float* __restrict__ sc)
{
  float* row = sc + (size_t)blockIdx.x * LP1;
  __shared__ float sh[4];
  const int t = threadIdx.x;
  float m = -1e30f;
  for (int i = t; i < LP1; i += 256) m = fmaxf(m, row[i]);
  #pragma unroll
  for (int o = 32; o; o >>= 1) m = fmaxf(m, __shfl_xor(m, o));
  if ((t & 63) == 0) sh[t >> 6] = m;
  __syncthreads();
  m = fmaxf(fmaxf(sh[0], sh[1]), fmaxf(sh[2], sh[3]));
  __syncthreads();
  float s = 0.f;
  for (int i = t; i < LP1; i += 256) { float e = __expf(row[i] - m); row[i] = e; s += e; }
  #pragma unroll
  for (int o = 32; o; o >>= 1) s += __shfl_xor(s, o);
  if ((t & 63) == 0) sh[t >> 6] = s;
  __syncthreads();
  float inv = 1.f / (sh[0] + sh[1] + sh[2] + sh[3]);
  for (int i = t; i < LP1; i += 256) row[i] *= inv;
}

__global__ __launch_bounds__(256) void gpv_kernel(
    const float* __restrict__ sc, const ushort_t* __restrict__ vg,
    float* __restrict__ parts)
{
  __shared__ float red[4][64];
  const int bh = blockIdx.y;
  const int b = bh >> 3, h = bh & 7;
  const int c = blockIdx.x;
  const int lane = threadIdx.x & 63, s4 = threadIdx.x >> 6;
  const int j0 = c * 512;
  const int jend = (j0 + 512 < LP1) ? j0 + 512 : LP1;
  const float* prow = sc + (size_t)bh * LP1;
  const ushort_t* vbase = vg + (size_t)b * LP1 * E + h * 64 + lane;
  float acc = 0.f;
  for (int j = j0 + s4; j < jend; j += 4)
    acc += prow[j] * b2f(vbase[(size_t)j * E]);
  red[s4][lane] = acc;
  __syncthreads();
  if (s4 == 0)
    parts[((size_t)c * 16 + bh) * 64 + lane] = red[0][lane] + red[1][lane] + red[2][lane] + red[3][lane];
}

__global__ void gpv_reduce(const float* __restrict__ parts, float* __restrict__ oc)
{
  int i = blockIdx.x * 256 + threadIdx.x;
  if (i < BB * E) {
    float s = 0.f;
    #pragma unroll
    for (int c = 0; c < 9; ++c) s += parts[c * 1024 + i];
    oc[i] = s;
  }
}

__global__ __launch_bounds__(256) void xcls_kernel(
    const float* __restrict__ oc, const float* __restrict__ ow,
    const float* __restrict__ ob, float* __restrict__ xc)
{
  int i = blockIdx.x * 256 + threadIdx.x;
  if (i >= BB * E) return;
  int b = i >> 9, n = i & 511;
  const float* o = oc + b * E;
  const float* wr = ow + (size_t)n * E;
  float s = ob[n];
  for (int m = 0; m < E; ++m) s += o[m] * wr[m];
  xc[i] = s;
}

// ---------------- fp32 -> bf16 weight convert ----------------
__global__ void cvt_kernel(const float* __restrict__ s, ushort_t* __restrict__ d, int n)
{
  int i = (blockIdx.x * 256 + threadIdx.x) * 4;
  if (i < n) {
    float4 v = *reinterpret_cast<const float4*>(s + i);
    ushort4 o;
    o.x = f2b(v.x); o.y = f2b(v.y); o.z = f2b(v.z); o.w = f2b(v.w);
    *reinterpret_cast<ushort4*>(d + i) = o;
  }
}

// ---------------- launch ----------------
extern "C" void kernel_launch(void* const* d_in, const int* in_sizes, int n_in,
                              void* d_out, int out_size, void* d_ws, size_t ws_size,
                              hipStream_t stream)
{
  const float* x      = (const float*)d_in[0];
  const float* ln1_g  = (const float*)d_in[1];
  const float* ln1_b  = (const float*)d_in[2];
  const float* qkv_w  = (const float*)d_in[3];
  const float* qkv_b  = (const float*)d_in[4];
  const float* na_w   = (const float*)d_in[5];
  const float* na_b   = (const float*)d_in[6];
  const float* in_w   = (const float*)d_in[7];
  const float* in_b   = (const float*)d_in[8];
  const float* out_w  = (const float*)d_in[9];
  const float* out_b  = (const float*)d_in[10];
  const float* ln2_g  = (const float*)d_in[11];
  const float* ln2_b  = (const float*)d_in[12];
  const float* fc1_w  = (const float*)d_in[13];
  const float* fc1_b  = (const float*)d_in[14];
  const float* fc2_w  = (const float*)d_in[15];
  const float* fc2_b  = (const float*)d_in[16];
  float* out = (float*)d_out;

  char* p = (char*)d_ws;
  size_t off = 0;
  auto alloc = [&](size_t bytes) {
    void* r = p + off; off = (off + bytes + 255) & ~(size_t)255; return r;
  };
  ushort_t* w_qkv = (ushort_t*)alloc((size_t)3 * E * E * 2);
  ushort_t* w_na  = (ushort_t*)alloc((size_t)E * E * 2);
  ushort_t* w_in  = (ushort_t*)alloc((size_t)3 * E * E * 2);
  ushort_t* w_fc1 = (ushort_t*)alloc((size_t)FDIM * E * 2);
  ushort_t* w_fc2 = (ushort_t*)alloc((size_t)E * FDIM * 2);
  ushort_t* xn1   = (ushort_t*)alloc((size_t)NTOK * E * 2);     // reused as xn2
  char*     bigR  = (char*)alloc((size_t)NTOK * FDIM * 2);      // phase-shared region
  ushort_t* qkvb  = (ushort_t*)bigR;                            // phase A: qkv (25.2MB)
  ushort_t* natt  = (ushort_t*)(bigR + (size_t)NLOC * 3 * E * 2); // phase A: natten out
  ushort_t* kgl   = (ushort_t*)bigR;                            // phase B: global K
  ushort_t* vgl   = (ushort_t*)(bigR + (size_t)NTOK * E * 2 + 256); // phase B: global V
  ushort_t* hbuf  = (ushort_t*)bigR;                            // phase C: MLP hidden
  ushort_t* tmpk  = (ushort_t*)alloc((size_t)NTOK * E * 2);
  float*    sc    = (float*)alloc((size_t)BB * H * LP1 * 4);
  float*    qcls  = (float*)alloc(1024 * 4);
  float*    parts = (float*)alloc(9 * 16 * 64 * 4);
  float*    oc    = (float*)alloc(1024 * 4);
  float*    xcls  = (float*)alloc(1024 * 4);
  float*    xa    = (float*)alloc((size_t)NTOK * E * 4);
  ushort_t* xn2   = xn1;

  // weight converts (fp32 -> bf16)
  cvt_kernel<<<3 * E * E / 1024, 256, 0, stream>>>(qkv_w, w_qkv, 3 * E * E);
  cvt_kernel<<<E * E / 1024, 256, 0, stream>>>(na_w, w_na, E * E);
  cvt_kernel<<<3 * E * E / 1024, 256, 0, stream>>>(in_w, w_in, 3 * E * E);
  cvt_kernel<<<FDIM * E / 1024, 256, 0, stream>>>(fc1_w, w_fc1, FDIM * E);
  cvt_kernel<<<E * FDIM / 1024, 256, 0, stream>>>(fc2_w, w_fc2, E * FDIM);

  // LN1 (+ tmp_key cls rows)
  ln_fused1<<<NTOK, 256, 0, stream>>>(x, ln1_g, ln1_b, xn1, tmpk);
  // CLS query projection (fp32 weights directly)
  qcls_kernel<<<4, 256, 0, stream>>>(xn1, in_w, in_b, qcls);
  // QKV for local tokens (input rows remapped past cls rows)
  gemm_bt<0,0,0,1,0><<<dim3(NLOC / BM, 3 * E / BN), 256, 0, stream>>>(
      xn1, w_qkv, qkv_b, nullptr, qkvb, nullptr, NLOC, 3 * E, E);
  // neighborhood attention
  natten_kernel<<<(BB * LL * H) / 4, 256, 0, stream>>>(qkvb, natt);
  // output projection -> tmp_key rows (remapped past cls rows)
  gemm_bt<0,0,0,0,1><<<dim3(NLOC / BM, E / BN), 256, 0, stream>>>(
      natt, w_na, na_b, nullptr, tmpk, nullptr, NLOC, E, E);
  // global K/V projections over tmp_key
  gemm_bt<0,0,0,0,0><<<dim3((NTOK + BM - 1) / BM, E / BN), 256, 0, stream>>>(
      tmpk, w_in + (size_t)E * E, in_b + E, nullptr, kgl, nullptr, NTOK, E, E);
  gemm_bt<0,0,0,0,0><<<dim3((NTOK + BM - 1) / BM, E / BN), 256, 0, stream>>>(
      tmpk, w_in + (size_t)2 * E * E, in_b + 2 * E, nullptr, vgl, nullptr, NTOK, E, E);
  // CLS attention: scores -> softmax -> PV -> out-proj
  gscore_kernel<<<(BB * LP1 + 3) / 4, 256, 0, stream>>>(qcls, kgl, sc);
  gsoftmax_kernel<<<BB * H, 256, 0, stream>>>(sc);
  gpv_kernel<<<dim3(9, BB * H), 256, 0, stream>>>(sc, vgl, parts);
  gpv_reduce<<<4, 256, 0, stream>>>(parts, oc);
  xcls_kernel<<<4, 256, 0, stream>>>(oc, out_w, out_b, xcls);
  // residual + LN2
  resid_ln2<<<NTOK, 256, 0, stream>>>(x, tmpk, xcls, ln2_g, ln2_b, xa, xn2);
  // MLP
  gemm_bt<1,0,0,0,0><<<dim3((NTOK + BM - 1) / BM, FDIM / BN), 256, 0, stream>>>(
      xn2, w_fc1, fc1_b, nullptr, hbuf, nullptr, NTOK, FDIM, E);
  gemm_bt<0,1,1,0,0><<<dim3((NTOK + BM - 1) / BM, E / BN), 256, 0, stream>>>(
      hbuf, w_fc2, fc2_b, out, nullptr, xa, NTOK, E, FDIM);
}

// Round 2
// 290.532 us; speedup vs baseline: 1.2613x; 1.2613x over previous
//
#include <hip/hip_runtime.h>
#include <hip/hip_bf16.h>
#include <cstdint>
#include <cstddef>

// ---------------- problem constants ----------------
#define E    512
#define H    8
#define DHD  64
#define FDIM 2048
#define KS   33
#define BB   2
#define LL   4096
#define LP1  4097
#define NTOK 8194   // BB*LP1
#define NLOC 8192   // BB*LL

typedef unsigned short ushort_t;
typedef __bf16 bf16x8_t __attribute__((ext_vector_type(8)));
typedef float  f32x4_t  __attribute__((ext_vector_type(4)));

__device__ __forceinline__ float b2f(unsigned short h) {
  union { unsigned int u; float f; } un; un.u = ((unsigned int)h) << 16; return un.f;
}
__device__ __forceinline__ unsigned short f2b(float f) {
  union { float f; unsigned int u; } un; un.f = f;
  unsigned int u = un.u;
  return (unsigned short)((u + 0x7FFFu + ((u >> 16) & 1u)) >> 16);
}

__device__ __forceinline__ void gload16(const ushort_t* g, ushort_t* l) {
  __builtin_amdgcn_global_load_lds(
      (const __attribute__((address_space(1))) void*)g,
      (__attribute__((address_space(3))) void*)l,
      16, 0, 0);
}

// ---------------- bf16 MFMA GEMM:  C = A(MxK) @ W(NxK)^T + bias ----------------
#define BM 128
#define BN 128
#define BK 32

template<int ACT, int OUTF, int ADDRES, int INRM, int OUTRM>
__global__ __launch_bounds__(256) void gemm_bt(
    const ushort_t* __restrict__ A, const ushort_t* __restrict__ W,
    const float* __restrict__ bias, float* __restrict__ outF,
    ushort_t* __restrict__ outB, const float* __restrict__ res,
    int M, int N, int K)
{
  __shared__ ushort_t Alds[BM * BK];
  __shared__ ushort_t Blds[BN * BK];
  const int t    = threadIdx.x;
  const int lane = t & 63;
  const int w    = t >> 6;
  const int wr   = w >> 1, wc = w & 1;
  const int bmBase = blockIdx.x * BM;
  const int bnBase = blockIdx.y * BN;

  f32x4_t zero = {0.f, 0.f, 0.f, 0.f};
  f32x4_t acc[4][4];
  #pragma unroll
  for (int m = 0; m < 4; ++m)
    #pragma unroll
    for (int n = 0; n < 4; ++n) acc[m][n] = zero;

  int r0 = bmBase + (t >> 2);
  int r1 = r0 + 64;
  if (INRM) { r0 += r0 >> 12; r1 += r1 >> 12; }
  else      { if (r0 >= M) r0 = M - 1; if (r1 >= M) r1 = M - 1; }
  const int ako = (t & 3) * 8;
  const int n0  = bnBase + (t >> 2);
  const int n1  = n0 + 64;

  const int frow = lane & 15;
  const int fk   = (lane >> 4) * 8;

  for (int k0 = 0; k0 < K; k0 += BK) {
    gload16(A + (size_t)r0 * K + k0 + ako, &Alds[(size_t)t * 8]);
    gload16(A + (size_t)r1 * K + k0 + ako, &Alds[(size_t)(256 + t) * 8]);
    gload16(W + (size_t)n0 * K + k0 + ako, &Blds[(size_t)t * 8]);
    gload16(W + (size_t)n1 * K + k0 + ako, &Blds[(size_t)(256 + t) * 8]);
    __syncthreads();
    bf16x8_t af[4], bfr[4];
    #pragma unroll
    for (int m = 0; m < 4; ++m)
      af[m] = *reinterpret_cast<const bf16x8_t*>(&Alds[(wr * 64 + m * 16 + frow) * BK + fk]);
    #pragma unroll
    for (int n = 0; n < 4; ++n)
      bfr[n] = *reinterpret_cast<const bf16x8_t*>(&Blds[(wc * 64 + n * 16 + frow) * BK + fk]);
    #pragma unroll
    for (int m = 0; m < 4; ++m)
      #pragma unroll
      for (int n = 0; n < 4; ++n)
        acc[m][n] = __builtin_amdgcn_mfma_f32_16x16x32_bf16(af[m], bfr[n], acc[m][n], 0, 0, 0);
    __syncthreads();
  }

  const int rbase = (lane >> 4) * 4;
  const int cbase = lane & 15;
  #pragma unroll
  for (int m = 0; m < 4; ++m) {
    #pragma unroll
    for (int r = 0; r < 4; ++r) {
      int gr = bmBase + wr * 64 + m * 16 + rbase + r;
      if (gr < M) {
        int orow = OUTRM ? gr + (gr >> 12) : gr;
        #pragma unroll
        for (int n = 0; n < 4; ++n) {
          int gc = bnBase + wc * 64 + n * 16 + cbase;
          float v = acc[m][n][r] + bias[gc];
          if (ACT == 1) v = v / (1.f + __expf(-v));
          if (ADDRES) v += res[(size_t)gr * N + gc];
          if (OUTF) outF[(size_t)orow * N + gc] = v;
          else      outB[(size_t)orow * N + gc] = f2b(v);
        }
      }
    }
  }
}

// ---------------- LN1 (also copies cls rows into tmp_key) ----------------
__global__ __launch_bounds__(256) void ln_fused1(
    const float* __restrict__ x, const float* __restrict__ g,
    const float* __restrict__ be, ushort_t* __restrict__ xn,
    ushort_t* __restrict__ tmpk)
{
  __shared__ float sh[4];
  const int row = blockIdx.x;
  const int t = threadIdx.x;
  const float* xr = x + (size_t)row * E;
  float v0 = xr[t], v1 = xr[t + 256];
  float sum = v0 + v1;
  #pragma unroll
  for (int o = 32; o; o >>= 1) sum += __shfl_xor(sum, o);
  if ((t & 63) == 0) sh[t >> 6] = sum;
  __syncthreads();
  float mean = (sh[0] + sh[1] + sh[2] + sh[3]) * (1.f / E);
  __syncthreads();
  float d0 = v0 - mean, d1 = v1 - mean;
  float vs = d0 * d0 + d1 * d1;
  #pragma unroll
  for (int o = 32; o; o >>= 1) vs += __shfl_xor(vs, o);
  if ((t & 63) == 0) sh[t >> 6] = vs;
  __syncthreads();
  float var = (sh[0] + sh[1] + sh[2] + sh[3]) * (1.f / E);
  float rstd = rsqrtf(var + 1e-5f);
  unsigned short o0 = f2b(d0 * rstd * g[t] + be[t]);
  unsigned short o1 = f2b(d1 * rstd * g[t + 256] + be[t + 256]);
  xn[(size_t)row * E + t] = o0;
  xn[(size_t)row * E + t + 256] = o1;
  if ((row % LP1) == LL) {
    tmpk[(size_t)row * E + t] = o0;
    tmpk[(size_t)row * E + t + 256] = o1;
  }
}

// ---------------- residual-add + LN2 ----------------
__global__ __launch_bounds__(256) void resid_ln2(
    const float* __restrict__ x, const ushort_t* __restrict__ tmpk,
    const float* __restrict__ xcls, const float* __restrict__ g,
    const float* __restrict__ be, float* __restrict__ xa,
    ushort_t* __restrict__ xn2)
{
  __shared__ float sh[4];
  const int row = blockIdx.x;
  const int b = row / LP1, l = row % LP1;
  const int t = threadIdx.x;
  float a0, a1;
  if (l < LL) { a0 = b2f(tmpk[(size_t)row * E + t]); a1 = b2f(tmpk[(size_t)row * E + t + 256]); }
  else        { a0 = xcls[b * E + t];                a1 = xcls[b * E + t + 256]; }
  float v0 = x[(size_t)row * E + t] + a0;
  float v1 = x[(size_t)row * E + t + 256] + a1;
  xa[(size_t)row * E + t] = v0;
  xa[(size_t)row * E + t + 256] = v1;
  float sum = v0 + v1;
  #pragma unroll
  for (int o = 32; o; o >>= 1) sum += __shfl_xor(sum, o);
  if ((t & 63) == 0) sh[t >> 6] = sum;
  __syncthreads();
  float mean = (sh[0] + sh[1] + sh[2] + sh[3]) * (1.f / E);
  __syncthreads();
  float d0 = v0 - mean, d1 = v1 - mean;
  float vs = d0 * d0 + d1 * d1;
  #pragma unroll
  for (int o = 32; o; o >>= 1) vs += __shfl_xor(vs, o);
  if ((t & 63) == 0) sh[t >> 6] = vs;
  __syncthreads();
  float var = (sh[0] + sh[1] + sh[2] + sh[3]) * (1.f / E);
  float rstd = rsqrtf(var + 1e-5f);
  xn2[(size_t)row * E + t]       = f2b(d0 * rstd * g[t] + be[t]);
  xn2[(size_t)row * E + t + 256] = f2b(d1 * rstd * g[t + 256] + be[t + 256]);
}

// ---------------- neighborhood attention via MFMA ----------------
// One wave per (b, h, 32-query tile). Window union of 32 queries = exactly
// 64 keys [l0-16, l0+47] (clipped; invalid masked). QK^T: 16 MFMAs,
// in-register masked softmax (4-shuffle row reduce), P->LDS, PV: 16 MFMAs
// with V^T staged in LDS. Waves independent -> no barriers.
__global__ __launch_bounds__(256) void natten_mfma(
    const ushort_t* __restrict__ qkv, ushort_t* __restrict__ out)
{
  __shared__ ushort_t KP[4][64 * 64];   // K tile (XOR-swizzled); reused for P [32][72]
  __shared__ ushort_t VT[4][64 * 72];   // V^T, stride 72 elems
  const int w    = threadIdx.x >> 6;
  const int lane = threadIdx.x & 63;
  const int task = blockIdx.x * 4 + w;
  const int h  = task & 7;
  const int qb = (task >> 3) & 127;
  const int b  = task >> 10;
  const int l0 = qb * 32;
  const int kb = l0 - 16;
  const ushort_t* base = qkv + (size_t)b * LL * (3 * E);
  ushort_t* Klds = KP[w];
  ushort_t* Vt   = VT[w];

  // ---- stage K (row-major, byte ^= (row&7)<<4) ----
  {
    const int rsub = lane >> 3;          // 0..7
    const int d0   = (lane & 7) * 8;     // 0..56
    #pragma unroll
    for (int i = 0; i < 8; ++i) {
      int row = i * 8 + rsub;
      int gl = kb + row; gl = gl < 0 ? 0 : (gl > LL - 1 ? LL - 1 : gl);
      bf16x8_t kv = *reinterpret_cast<const bf16x8_t*>(
          base + (size_t)gl * (3 * E) + E + h * 64 + d0);
      int ba = (row * 128 + d0 * 2) ^ ((row & 7) << 4);
      *reinterpret_cast<bf16x8_t*>((char*)Klds + ba) = kv;
    }
  }
  // ---- stage V^T (packed row-pairs -> u32 writes), stride 72 ----
  {
    const int a  = lane & 7;             // d-chunk
    const int c8 = lane >> 3;            // row-pair selector
    unsigned int* Vt32 = (unsigned int*)Vt;
    #pragma unroll
    for (int i = 0; i < 4; ++i) {
      int rp = i * 8 + c8;               // 0..31
      int g0 = kb + rp * 2;     g0 = g0 < 0 ? 0 : (g0 > LL - 1 ? LL - 1 : g0);
      int g1 = kb + rp * 2 + 1; g1 = g1 < 0 ? 0 : (g1 > LL - 1 ? LL - 1 : g1);
      const ushort_t* v0 = base + (size_t)g0 * (3 * E) + 2 * E + h * 64 + a * 8;
      const ushort_t* v1 = base + (size_t)g1 * (3 * E) + 2 * E + h * 64 + a * 8;
      ushort4 x0 = *(const ushort4*)v0,       x1 = *(const ushort4*)v1;
      ushort4 y0 = *(const ushort4*)(v0 + 4), y1 = *(const ushort4*)(v1 + 4);
      int d = a * 8;
      Vt32[(d + 0) * 36 + rp] = (unsigned)x0.x | ((unsigned)x1.x << 16);
      Vt32[(d + 1) * 36 + rp] = (unsigned)x0.y | ((unsigned)x1.y << 16);
      Vt32[(d + 2) * 36 + rp] = (unsigned)x0.z | ((unsigned)x1.z << 16);
      Vt32[(d + 3) * 36 + rp] = (unsigned)x0.w | ((unsigned)x1.w << 16);
      Vt32[(d + 4) * 36 + rp] = (unsigned)y0.x | ((unsigned)y1.x << 16);
      Vt32[(d + 5) * 36 + rp] = (unsigned)y0.y | ((unsigned)y1.y << 16);
      Vt32[(d + 6) * 36 + rp] = (unsigned)y0.z | ((unsigned)y1.z << 16);
      Vt32[(d + 7) * 36 + rp] = (unsigned)y0.w | ((unsigned)y1.w << 16);
    }
  }

  // ---- Q fragments straight from global (L2-resident) ----
  const int p = lane & 15, g = lane >> 4;
  bf16x8_t qf[2][2];
  #pragma unroll
  for (int mt = 0; mt < 2; ++mt)
    #pragma unroll
    for (int ks = 0; ks < 2; ++ks)
      qf[mt][ks] = *reinterpret_cast<const bf16x8_t*>(
          base + (size_t)(l0 + mt * 16 + p) * (3 * E) + h * 64 + ks * 32 + g * 8);

  // ---- S = Q @ K^T ----
  f32x4_t zero = {0.f, 0.f, 0.f, 0.f};
  f32x4_t accS[2][4];
  #pragma unroll
  for (int mt = 0; mt < 2; ++mt)
    #pragma unroll
    for (int nt = 0; nt < 4; ++nt) accS[mt][nt] = zero;
  #pragma unroll
  for (int ks = 0; ks < 2; ++ks) {
    bf16x8_t kf[4];
    #pragma unroll
    for (int nt = 0; nt < 4; ++nt) {
      int row = nt * 16 + p;
      int ba = (row * 128 + (ks * 32 + g * 8) * 2) ^ ((row & 7) << 4);
      kf[nt] = *reinterpret_cast<const bf16x8_t*>((char*)Klds + ba);
    }
    #pragma unroll
    for (int mt = 0; mt < 2; ++mt)
      #pragma unroll
      for (int nt = 0; nt < 4; ++nt)
        accS[mt][nt] = __builtin_amdgcn_mfma_f32_16x16x32_bf16(qf[mt][ks], kf[nt], accS[mt][nt], 0, 0, 0);
  }

  // ---- masked softmax per q-row; write P (bf16) into Klds region [32][72] ----
  ushort_t* Plds = Klds;
  #pragma unroll
  for (int mt = 0; mt < 2; ++mt) {
    #pragma unroll
    for (int r = 0; r < 4; ++r) {
      int lq = l0 + mt * 16 + g * 4 + r;
      int st = lq - 16; st = st < 0 ? 0 : (st > LL - KS ? LL - KS : st);
      int clo = st - kb, chi = clo + 32;
      float sv[4];
      float mx = -1e30f;
      #pragma unroll
      for (int nt = 0; nt < 4; ++nt) {
        int c = nt * 16 + p;
        float s = accS[mt][nt][r] * 0.125f;
        s = (c >= clo && c <= chi) ? s : -1e30f;
        sv[nt] = s;
        mx = fmaxf(mx, s);
      }
      mx = fmaxf(mx, __shfl_xor(mx, 1));
      mx = fmaxf(mx, __shfl_xor(mx, 2));
      mx = fmaxf(mx, __shfl_xor(mx, 4));
      mx = fmaxf(mx, __shfl_xor(mx, 8));
      float sum = 0.f;
      #pragma unroll
      for (int nt = 0; nt < 4; ++nt) { float e = __expf(sv[nt] - mx); sv[nt] = e; sum += e; }
      sum += __shfl_xor(sum, 1);
      sum += __shfl_xor(sum, 2);
      sum += __shfl_xor(sum, 4);
      sum += __shfl_xor(sum, 8);
      float inv = 1.f / sum;
      int q = mt * 16 + g * 4 + r;
      #pragma unroll
      for (int nt = 0; nt < 4; ++nt)
        Plds[q * 72 + nt * 16 + p] = f2b(sv[nt] * inv);
    }
  }

  // ---- O = P @ V ----
  f32x4_t accO[2][4];
  #pragma unroll
  for (int mt = 0; mt < 2; ++mt)
    #pragma unroll
    for (int nt = 0; nt < 4; ++nt) accO[mt][nt] = zero;
  #pragma unroll
  for (int ks = 0; ks < 2; ++ks) {
    bf16x8_t pf[2], vf[4];
    #pragma unroll
    for (int mt = 0; mt < 2; ++mt)
      pf[mt] = *reinterpret_cast<const bf16x8_t*>(
          (char*)Plds + (mt * 16 + p) * 144 + (ks * 32 + g * 8) * 2);
    #pragma unroll
    for (int nt = 0; nt < 4; ++nt)
      vf[nt] = *reinterpret_cast<const bf16x8_t*>(
          (char*)Vt + (nt * 16 + p) * 144 + (ks * 32 + g * 8) * 2);
    #pragma unroll
    for (int mt = 0; mt < 2; ++mt)
      #pragma unroll
      for (int nt = 0; nt < 4; ++nt)
        accO[mt][nt] = __builtin_amdgcn_mfma_f32_16x16x32_bf16(pf[mt], vf[nt], accO[mt][nt], 0, 0, 0);
  }

  // ---- store O ----
  #pragma unroll
  for (int mt = 0; mt < 2; ++mt) {
    #pragma unroll
    for (int r = 0; r < 4; ++r) {
      int lq = l0 + mt * 16 + g * 4 + r;
      ushort_t* orow = out + ((size_t)(b * LL) + lq) * E + h * 64;
      #pragma unroll
      for (int nt = 0; nt < 4; ++nt)
        orow[nt * 16 + p] = f2b(accO[mt][nt][r]);
    }
  }
}

// ---------------- global MHA pieces (CLS query) ----------------
__global__ __launch_bounds__(256) void qcls_kernel(
    const ushort_t* __restrict__ xn, const float* __restrict__ inw,
    const float* __restrict__ inb, float* __restrict__ qcls)
{
  int i = blockIdx.x * 256 + threadIdx.x;
  int b = i >> 9, d = i & 511;
  const ushort_t* xr = xn + ((size_t)b * LP1 + LL) * E;
  const float* wr = inw + (size_t)d * E;
  float s = 0.f;
  for (int e = 0; e < E; e += 4) {
    ushort4 xv = *reinterpret_cast<const ushort4*>(xr + e);
    s += b2f(xv.x) * wr[e] + b2f(xv.y) * wr[e + 1] + b2f(xv.z) * wr[e + 2] + b2f(xv.w) * wr[e + 3];
  }
  qcls[i] = (s + inb[d]) * 0.125f;
}

// kv buffer layout: [NTOK][1024], K = cols 0..511, V = cols 512..1023
__global__ __launch_bounds__(256) void gscore_kernel(
    const float* __restrict__ qcls, const ushort_t* __restrict__ kv,
    float* __restrict__ sc)
{
  const int wav = blockIdx.x * 4 + (threadIdx.x >> 6);
  if (wav >= BB * LP1) return;
  const int lane = threadIdx.x & 63;
  const int b = wav / LP1, j = wav % LP1;
  const ushort_t* kr = kv + (size_t)wav * 1024 + lane * 8;
  const float* q = qcls + b * E + lane * 8;
  ushort4 ka = *reinterpret_cast<const ushort4*>(kr);
  ushort4 kb4 = *reinterpret_cast<const ushort4*>(kr + 4);
  float s = b2f(ka.x) * q[0] + b2f(ka.y) * q[1] + b2f(ka.z) * q[2] + b2f(ka.w) * q[3]
          + b2f(kb4.x) * q[4] + b2f(kb4.y) * q[5] + b2f(kb4.z) * q[6] + b2f(kb4.w) * q[7];
  s += __shfl_xor(s, 1); s += __shfl_xor(s, 2); s += __shfl_xor(s, 4);
  if ((lane & 7) == 0) sc[((size_t)(b * 8) + (lane >> 3)) * LP1 + j] = s;
}

__global__ __launch_bounds__(256) void gsoftmax_kernel(float* __restrict__ sc)
{
  float* row = sc + (size_t)blockIdx.x * LP1;
  __shared__ float sh[4];
  const int t = threadIdx.x;
  float m = -1e30f;
  for (int i = t; i < LP1; i += 256) m = fmaxf(m, row[i]);
  #pragma unroll
  for (int o = 32; o; o >>= 1) m = fmaxf(m, __shfl_xor(m, o));
  if ((t & 63) == 0) sh[t >> 6] = m;
  __syncthreads();
  m = fmaxf(fmaxf(sh[0], sh[1]), fmaxf(sh[2], sh[3]));
  __syncthreads();
  float s = 0.f;
  for (int i = t; i < LP1; i += 256) { float e = __expf(row[i] - m); row[i] = e; s += e; }
  #pragma unroll
  for (int o = 32; o; o >>= 1) s += __shfl_xor(s, o);
  if ((t & 63) == 0) sh[t >> 6] = s;
  __syncthreads();
  float inv = 1.f / (sh[0] + sh[1] + sh[2] + sh[3]);
  for (int i = t; i < LP1; i += 256) row[i] *= inv;
}

__global__ __launch_bounds__(256) void gpv_kernel(
    const float* __restrict__ sc, const ushort_t* __restrict__ kv,
    float* __restrict__ parts)
{
  __shared__ float red[4][64];
  const int bh = blockIdx.y;
  const int b = bh >> 3, h = bh & 7;
  const int c = blockIdx.x;
  const int lane = threadIdx.x & 63, s4 = threadIdx.x >> 6;
  const int j0 = c * 512;
  const int jend = (j0 + 512 < LP1) ? j0 + 512 : LP1;
  const float* prow = sc + (size_t)bh * LP1;
  const ushort_t* vbase = kv + (size_t)b * LP1 * 1024 + 512 + h * 64 + lane;
  float acc = 0.f;
  for (int j = j0 + s4; j < jend; j += 4)
    acc += prow[j] * b2f(vbase[(size_t)j * 1024]);
  red[s4][lane] = acc;
  __syncthreads();
  if (s4 == 0)
    parts[((size_t)c * 16 + bh) * 64 + lane] = red[0][lane] + red[1][lane] + red[2][lane] + red[3][lane];
}

__global__ void gpv_reduce(const float* __restrict__ parts, float* __restrict__ oc)
{
  int i = blockIdx.x * 256 + threadIdx.x;
  if (i < BB * E) {
    float s = 0.f;
    #pragma unroll
    for (int c = 0; c < 9; ++c) s += parts[c * 1024 + i];
    oc[i] = s;
  }
}

__global__ __launch_bounds__(256) void xcls_kernel(
    const float* __restrict__ oc, const float* __restrict__ ow,
    const float* __restrict__ ob, float* __restrict__ xc)
{
  int i = blockIdx.x * 256 + threadIdx.x;
  if (i >= BB * E) return;
  int b = i >> 9, n = i & 511;
  const float* o = oc + b * E;
  const float* wr = ow + (size_t)n * E;
  float s = ob[n];
  for (int m = 0; m < E; ++m) s += o[m] * wr[m];
  xc[i] = s;
}

// ---------------- fused fp32 -> bf16 weight convert (all 5 weights) ----------------
__global__ void cvt_all(
    const float* __restrict__ s0, ushort_t* __restrict__ d0, int n0,
    const float* __restrict__ s1, ushort_t* __restrict__ d1, int n1,
    const float* __restrict__ s2, ushort_t* __restrict__ d2, int n2,
    const float* __restrict__ s3, ushort_t* __restrict__ d3, int n3,
    const float* __restrict__ s4, ushort_t* __restrict__ d4, int n4)
{
  int i = (blockIdx.x * 256 + threadIdx.x) * 4;
  const float* s; ushort_t* d;
  if (i < n0)                { s = s0; d = d0; }
  else if ((i -= n0) < n1)   { s = s1; d = d1; }
  else if ((i -= n1) < n2)   { s = s2; d = d2; }
  else if ((i -= n2) < n3)   { s = s3; d = d3; }
  else if ((i -= n3) < n4)   { s = s4; d = d4; }
  else return;
  float4 v = *reinterpret_cast<const float4*>(s + i);
  ushort4 o;
  o.x = f2b(v.x); o.y = f2b(v.y); o.z = f2b(v.z); o.w = f2b(v.w);
  *reinterpret_cast<ushort4*>(d + i) = o;
}

// ---------------- launch ----------------
extern "C" void kernel_launch(void* const* d_in, const int* in_sizes, int n_in,
                              void* d_out, int out_size, void* d_ws, size_t ws_size,
                              hipStream_t stream)
{
  const float* x      = (const float*)d_in[0];
  const float* ln1_g  = (const float*)d_in[1];
  const float* ln1_b  = (const float*)d_in[2];
  const float* qkv_w  = (const float*)d_in[3];
  const float* qkv_b  = (const float*)d_in[4];
  const float* na_w   = (const float*)d_in[5];
  const float* na_b   = (const float*)d_in[6];
  const float* in_w   = (const float*)d_in[7];
  const float* in_b   = (const float*)d_in[8];
  const float* out_w  = (const float*)d_in[9];
  const float* out_b  = (const float*)d_in[10];
  const float* ln2_g  = (const float*)d_in[11];
  const float* ln2_b  = (const float*)d_in[12];
  const float* fc1_w  = (const float*)d_in[13];
  const float* fc1_b  = (const float*)d_in[14];
  const float* fc2_w  = (const float*)d_in[15];
  const float* fc2_b  = (const float*)d_in[16];
  float* out = (float*)d_out;

  char* pws = (char*)d_ws;
  size_t off = 0;
  auto alloc = [&](size_t bytes) {
    void* r = pws + off; off = (off + bytes + 255) & ~(size_t)255; return r;
  };
  ushort_t* w_qkv = (ushort_t*)alloc((size_t)3 * E * E * 2);
  ushort_t* w_na  = (ushort_t*)alloc((size_t)E * E * 2);
  ushort_t* w_in  = (ushort_t*)alloc((size_t)3 * E * E * 2);
  ushort_t* w_fc1 = (ushort_t*)alloc((size_t)FDIM * E * 2);
  ushort_t* w_fc2 = (ushort_t*)alloc((size_t)E * FDIM * 2);
  ushort_t* xn1   = (ushort_t*)alloc((size_t)NTOK * E * 2);     // reused as xn2
  char*     bigR  = (char*)alloc((size_t)NTOK * FDIM * 2);      // phase-shared region
  ushort_t* qkvb  = (ushort_t*)bigR;                            // phase A: qkv
  ushort_t* natt  = (ushort_t*)(bigR + (size_t)NLOC * 3 * E * 2); // phase A: natten out
  ushort_t* kvg   = (ushort_t*)bigR;                            // phase B: fused K|V [NTOK][1024]
  ushort_t* hbuf  = (ushort_t*)bigR;                            // phase C: MLP hidden
  ushort_t* tmpk  = (ushort_t*)alloc((size_t)NTOK * E * 2);
  float*    sc    = (float*)alloc((size_t)BB * H * LP1 * 4);
  float*    qcls  = (float*)alloc(1024 * 4);
  float*    parts = (float*)alloc(9 * 16 * 64 * 4);
  float*    oc    = (float*)alloc(1024 * 4);
  float*    xcls  = (float*)alloc(1024 * 4);
  float*    xa    = (float*)alloc((size_t)NTOK * E * 4);
  ushort_t* xn2   = xn1;

  // fused weight converts
  cvt_all<<<3840, 256, 0, stream>>>(
      qkv_w, w_qkv, 3 * E * E,
      na_w,  w_na,  E * E,
      in_w,  w_in,  3 * E * E,
      fc1_w, w_fc1, FDIM * E,
      fc2_w, w_fc2, E * FDIM);

  // LN1 (+ tmp_key cls rows)
  ln_fused1<<<NTOK, 256, 0, stream>>>(x, ln1_g, ln1_b, xn1, tmpk);
  // CLS query projection
  qcls_kernel<<<4, 256, 0, stream>>>(xn1, in_w, in_b, qcls);
  // QKV for local tokens
  gemm_bt<0,0,0,1,0><<<dim3(NLOC / BM, 3 * E / BN), 256, 0, stream>>>(
      xn1, w_qkv, qkv_b, nullptr, qkvb, nullptr, NLOC, 3 * E, E);
  // neighborhood attention (MFMA)
  natten_mfma<<<512, 256, 0, stream>>>(qkvb, natt);
  // output projection -> tmp_key rows
  gemm_bt<0,0,0,0,1><<<dim3(NLOC / BM, E / BN), 256, 0, stream>>>(
      natt, w_na, na_b, nullptr, tmpk, nullptr, NLOC, E, E);
  // fused global K+V projection (rows E..3E of in_w are contiguous)
  gemm_bt<0,0,0,0,0><<<dim3((NTOK + BM - 1) / BM, 1024 / BN), 256, 0, stream>>>(
      tmpk, w_in + (size_t)E * E, in_b + E, nullptr, kvg, nullptr, NTOK, 1024, E);
  // CLS attention
  gscore_kernel<<<(BB * LP1 + 3) / 4, 256, 0, stream>>>(qcls, kvg, sc);
  gsoftmax_kernel<<<BB * H, 256, 0, stream>>>(sc);
  gpv_kernel<<<dim3(9, BB * H), 256, 0, stream>>>(sc, kvg, parts);
  gpv_reduce<<<4, 256, 0, stream>>>(parts, oc);
  xcls_kernel<<<4, 256, 0, stream>>>(oc, out_w, out_b, xcls);
  // residual + LN2
  resid_ln2<<<NTOK, 256, 0, stream>>>(x, tmpk, xcls, ln2_g, ln2_b, xa, xn2);
  // MLP
  gemm_bt<1,0,0,0,0><<<dim3((NTOK + BM - 1) / BM, FDIM / BN), 256, 0, stream>>>(
      xn2, w_fc1, fc1_b, nullptr, hbuf, nullptr, NTOK, FDIM, E);
  gemm_bt<0,1,1,0,0><<<dim3((NTOK + BM - 1) / BM, E / BN), 256, 0, stream>>>(
      hbuf, w_fc2, fc2_b, out, nullptr, xa, NTOK, E, FDIM);
}

// Round 3
// 287.512 us; speedup vs baseline: 1.2745x; 1.0105x over previous
//
#include <hip/hip_runtime.h>
#include <hip/hip_bf16.h>
#include <cstdint>
#include <cstddef>

// ---------------- problem constants ----------------
#define E    512
#define H    8
#define DHD  64
#define FDIM 2048
#define KS   33
#define BB   2
#define LL   4096
#define LP1  4097
#define NTOK 8194   // BB*LP1
#define NLOC 8192   // BB*LL

typedef unsigned short ushort_t;
typedef __bf16 bf16x8_t __attribute__((ext_vector_type(8)));
typedef float  f32x4_t  __attribute__((ext_vector_type(4)));

__device__ __forceinline__ float b2f(unsigned short h) {
  union { unsigned int u; float f; } un; un.u = ((unsigned int)h) << 16; return un.f;
}
__device__ __forceinline__ unsigned short f2b(float f) {
  union { float f; unsigned int u; } un; un.f = f;
  unsigned int u = un.u;
  return (unsigned short)((u + 0x7FFFu + ((u >> 16) & 1u)) >> 16);
}

__device__ __forceinline__ void gload16(const ushort_t* g, ushort_t* l) {
  __builtin_amdgcn_global_load_lds(
      (const __attribute__((address_space(1))) void*)g,
      (__attribute__((address_space(3))) void*)l,
      16, 0, 0);
}

// ---------------- bf16 MFMA GEMM:  C = A(MxK) @ W(NxK)^T + bias ----------------
// BK=64 (128B LDS rows), XOR-swizzled (quad ^= row&7) with pre-swizzled global
// source (rule #21: linear global_load_lds dest + swizzled ds_read). 4 waves
// 2x2. BNT = 128 or 64 (skinny-N / split-K variant). PARTIAL: raw fp32
// partial-sum output for split-K (blockIdx.z selects K-chunk and dest).
#define BM 128

template<int BNT, int ACT, int OUTF, int ADDRES, int INRM, int OUTRM, int PARTIAL>
__global__ __launch_bounds__(256) void gemm_bt(
    const ushort_t* __restrict__ A, const ushort_t* __restrict__ W,
    const float* __restrict__ bias, float* __restrict__ outF,
    ushort_t* __restrict__ outB, const float* __restrict__ res,
    int M, int N, int K, int klen)
{
  constexpr int NFRAG = BNT / 32;          // n-fragments per wave (4 or 2)
  __shared__ ushort_t Alds[BM * 64];
  __shared__ ushort_t Blds[BNT * 64];
  const int t    = threadIdx.x;
  const int lane = t & 63;
  const int w    = t >> 6;
  const int wr   = w >> 1, wc = w & 1;
  const int bmBase = blockIdx.x * BM;
  const int bnBase = blockIdx.y * BNT;
  const int z    = blockIdx.z;
  const int kbeg = z * klen;

  f32x4_t zero = {0.f, 0.f, 0.f, 0.f};
  f32x4_t acc[4][NFRAG];
  #pragma unroll
  for (int m = 0; m < 4; ++m)
    #pragma unroll
    for (int n = 0; n < NFRAG; ++n) acc[m][n] = zero;

  // staging map: chunk c = round*256+t -> row=c>>3, slot j=c&7 (16B chunks).
  // slot j holds logical k-chunk j^(row&7); row&7 == (t>>3)&7 for all rounds.
  const int srow = t >> 3;                 // 0..31
  const int jsw8 = ((t & 7) ^ (srow & 7)) * 8;   // pre-swizzled k-offset (elems)
  int arow[4];
  #pragma unroll
  for (int r = 0; r < 4; ++r) {
    int rr = bmBase + r * 32 + srow;
    if (INRM) rr += rr >> 12;              // local row -> padded row (skip cls)
    else if (rr >= M) rr = M - 1;
    arow[r] = rr;
  }
  int brow[NFRAG];
  #pragma unroll
  for (int r = 0; r < NFRAG; ++r) brow[r] = bnBase + r * 32 + srow;

  const int frow = lane & 15;
  const int g    = lane >> 4;

  for (int k0 = kbeg; k0 < kbeg + klen; k0 += 64) {
    #pragma unroll
    for (int r = 0; r < 4; ++r)
      gload16(A + (size_t)arow[r] * K + k0 + jsw8, &Alds[(size_t)(r * 256 + t) * 8]);
    #pragma unroll
    for (int r = 0; r < NFRAG; ++r)
      gload16(W + (size_t)brow[r] * K + k0 + jsw8, &Blds[(size_t)(r * 256 + t) * 8]);
    __syncthreads();   // vmcnt(0) drain -> tile ready
    #pragma unroll
    for (int kk2 = 0; kk2 < 2; ++kk2) {
      bf16x8_t af[4], bfv[NFRAG];
      const int kosw = ((kk2 * 4 + g) ^ (frow & 7)) << 4;   // swizzled byte offset in row
      #pragma unroll
      for (int m = 0; m < 4; ++m) {
        int row = wr * 64 + m * 16 + frow;
        af[m] = *reinterpret_cast<const bf16x8_t*>((char*)Alds + row * 128 + kosw);
      }
      #pragma unroll
      for (int n = 0; n < NFRAG; ++n) {
        int row = wc * (BNT / 2) + n * 16 + frow;
        bfv[n] = *reinterpret_cast<const bf16x8_t*>((char*)Blds + row * 128 + kosw);
      }
      #pragma unroll
      for (int m = 0; m < 4; ++m)
        #pragma unroll
        for (int n = 0; n < NFRAG; ++n)
          acc[m][n] = __builtin_amdgcn_mfma_f32_16x16x32_bf16(af[m], bfv[n], acc[m][n], 0, 0, 0);
    }
    __syncthreads();   // protect LDS before next stage
  }

  // epilogue: C/D layout col=lane&15, row=(lane>>4)*4+r
  const int rbase = g * 4;
  const int cbase = frow;
  float* po = nullptr;
  if (PARTIAL) po = (z == 0) ? outF : (float*)outB;
  #pragma unroll
  for (int m = 0; m < 4; ++m) {
    #pragma unroll
    for (int r = 0; r < 4; ++r) {
      int gr = bmBase + wr * 64 + m * 16 + rbase + r;
      if (gr < M) {
        int orow = OUTRM ? gr + (gr >> 12) : gr;
        #pragma unroll
        for (int n = 0; n < NFRAG; ++n) {
          int gc = bnBase + wc * (BNT / 2) + n * 16 + cbase;
          float v = acc[m][n][r];
          if (PARTIAL) {
            po[(size_t)orow * N + gc] = v;
          } else {
            v += bias[gc];
            if (ACT == 1) v = v / (1.f + __expf(-v));
            if (ADDRES) v += res[(size_t)gr * N + gc];
            if (OUTF) outF[(size_t)orow * N + gc] = v;
            else      outB[(size_t)orow * N + gc] = f2b(v);
          }
        }
      }
    }
  }
}

// ---------------- split-K reduce: out = out(P1) + P0 + bias + xa ----------------
__global__ __launch_bounds__(256) void fc2_reduce(
    float* __restrict__ out, const float* __restrict__ p0,
    const float* __restrict__ bias, const float* __restrict__ xa)
{
  size_t i = (size_t)blockIdx.x * 256 + threadIdx.x;   // float4 index
  float4 o = reinterpret_cast<const float4*>(out)[i];
  float4 a = reinterpret_cast<const float4*>(p0)[i];
  float4 x = reinterpret_cast<const float4*>(xa)[i];
  float4 bcol = reinterpret_cast<const float4*>(bias)[i & 127];
  o.x += a.x + x.x + bcol.x;
  o.y += a.y + x.y + bcol.y;
  o.z += a.z + x.z + bcol.z;
  o.w += a.w + x.w + bcol.w;
  reinterpret_cast<float4*>(out)[i] = o;
}

// ---------------- LN1 (also copies cls rows into tmp_key) ----------------
__global__ __launch_bounds__(256) void ln_fused1(
    const float* __restrict__ x, const float* __restrict__ g,
    const float* __restrict__ be, ushort_t* __restrict__ xn,
    ushort_t* __restrict__ tmpk)
{
  __shared__ float sh[4];
  const int row = blockIdx.x;
  const int t = threadIdx.x;
  const float* xr = x + (size_t)row * E;
  float v0 = xr[t], v1 = xr[t + 256];
  float sum = v0 + v1;
  #pragma unroll
  for (int o = 32; o; o >>= 1) sum += __shfl_xor(sum, o);
  if ((t & 63) == 0) sh[t >> 6] = sum;
  __syncthreads();
  float mean = (sh[0] + sh[1] + sh[2] + sh[3]) * (1.f / E);
  __syncthreads();
  float d0 = v0 - mean, d1 = v1 - mean;
  float vs = d0 * d0 + d1 * d1;
  #pragma unroll
  for (int o = 32; o; o >>= 1) vs += __shfl_xor(vs, o);
  if ((t & 63) == 0) sh[t >> 6] = vs;
  __syncthreads();
  float var = (sh[0] + sh[1] + sh[2] + sh[3]) * (1.f / E);
  float rstd = rsqrtf(var + 1e-5f);
  unsigned short o0 = f2b(d0 * rstd * g[t] + be[t]);
  unsigned short o1 = f2b(d1 * rstd * g[t + 256] + be[t + 256]);
  xn[(size_t)row * E + t] = o0;
  xn[(size_t)row * E + t + 256] = o1;
  if ((row % LP1) == LL) {
    tmpk[(size_t)row * E + t] = o0;
    tmpk[(size_t)row * E + t + 256] = o1;
  }
}

// ---------------- residual-add + LN2 ----------------
__global__ __launch_bounds__(256) void resid_ln2(
    const float* __restrict__ x, const ushort_t* __restrict__ tmpk,
    const float* __restrict__ xcls, const float* __restrict__ g,
    const float* __restrict__ be, float* __restrict__ xa,
    ushort_t* __restrict__ xn2)
{
  __shared__ float sh[4];
  const int row = blockIdx.x;
  const int b = row / LP1, l = row % LP1;
  const int t = threadIdx.x;
  float a0, a1;
  if (l < LL) { a0 = b2f(tmpk[(size_t)row * E + t]); a1 = b2f(tmpk[(size_t)row * E + t + 256]); }
  else        { a0 = xcls[b * E + t];                a1 = xcls[b * E + t + 256]; }
  float v0 = x[(size_t)row * E + t] + a0;
  float v1 = x[(size_t)row * E + t + 256] + a1;
  xa[(size_t)row * E + t] = v0;
  xa[(size_t)row * E + t + 256] = v1;
  float sum = v0 + v1;
  #pragma unroll
  for (int o = 32; o; o >>= 1) sum += __shfl_xor(sum, o);
  if ((t & 63) == 0) sh[t >> 6] = sum;
  __syncthreads();
  float mean = (sh[0] + sh[1] + sh[2] + sh[3]) * (1.f / E);
  __syncthreads();
  float d0 = v0 - mean, d1 = v1 - mean;
  float vs = d0 * d0 + d1 * d1;
  #pragma unroll
  for (int o = 32; o; o >>= 1) vs += __shfl_xor(vs, o);
  if ((t & 63) == 0) sh[t >> 6] = vs;
  __syncthreads();
  float var = (sh[0] + sh[1] + sh[2] + sh[3]) * (1.f / E);
  float rstd = rsqrtf(var + 1e-5f);
  xn2[(size_t)row * E + t]       = f2b(d0 * rstd * g[t] + be[t]);
  xn2[(size_t)row * E + t + 256] = f2b(d1 * rstd * g[t + 256] + be[t + 256]);
}

// ---------------- neighborhood attention via MFMA ----------------
__global__ __launch_bounds__(256) void natten_mfma(
    const ushort_t* __restrict__ qkv, ushort_t* __restrict__ out)
{
  __shared__ ushort_t KP[4][64 * 64];   // K tile (XOR-swizzled); reused for P [32][72]
  __shared__ ushort_t VT[4][64 * 72];   // V^T, stride 72 elems
  const int w    = threadIdx.x >> 6;
  const int lane = threadIdx.x & 63;
  const int task = blockIdx.x * 4 + w;
  const int h  = task & 7;
  const int qb = (task >> 3) & 127;
  const int b  = task >> 10;
  const int l0 = qb * 32;
  const int kb = l0 - 16;
  const ushort_t* base = qkv + (size_t)b * LL * (3 * E);
  ushort_t* Klds = KP[w];
  ushort_t* Vt   = VT[w];

  {
    const int rsub = lane >> 3;
    const int d0   = (lane & 7) * 8;
    #pragma unroll
    for (int i = 0; i < 8; ++i) {
      int row = i * 8 + rsub;
      int gl = kb + row; gl = gl < 0 ? 0 : (gl > LL - 1 ? LL - 1 : gl);
      bf16x8_t kv = *reinterpret_cast<const bf16x8_t*>(
          base + (size_t)gl * (3 * E) + E + h * 64 + d0);
      int ba = (row * 128 + d0 * 2) ^ ((row & 7) << 4);
      *reinterpret_cast<bf16x8_t*>((char*)Klds + ba) = kv;
    }
  }
  {
    const int a  = lane & 7;
    const int c8 = lane >> 3;
    unsigned int* Vt32 = (unsigned int*)Vt;
    #pragma unroll
    for (int i = 0; i < 4; ++i) {
      int rp = i * 8 + c8;
      int g0 = kb + rp * 2;     g0 = g0 < 0 ? 0 : (g0 > LL - 1 ? LL - 1 : g0);
      int g1 = kb + rp * 2 + 1; g1 = g1 < 0 ? 0 : (g1 > LL - 1 ? LL - 1 : g1);
      const ushort_t* v0 = base + (size_t)g0 * (3 * E) + 2 * E + h * 64 + a * 8;
      const ushort_t* v1 = base + (size_t)g1 * (3 * E) + 2 * E + h * 64 + a * 8;
      ushort4 x0 = *(const ushort4*)v0,       x1 = *(const ushort4*)v1;
      ushort4 y0 = *(const ushort4*)(v0 + 4), y1 = *(const ushort4*)(v1 + 4);
      int d = a * 8;
      Vt32[(d + 0) * 36 + rp] = (unsigned)x0.x | ((unsigned)x1.x << 16);
      Vt32[(d + 1) * 36 + rp] = (unsigned)x0.y | ((unsigned)x1.y << 16);
      Vt32[(d + 2) * 36 + rp] = (unsigned)x0.z | ((unsigned)x1.z << 16);
      Vt32[(d + 3) * 36 + rp] = (unsigned)x0.w | ((unsigned)x1.w << 16);
      Vt32[(d + 4) * 36 + rp] = (unsigned)y0.x | ((unsigned)y1.x << 16);
      Vt32[(d + 5) * 36 + rp] = (unsigned)y0.y | ((unsigned)y1.y << 16);
      Vt32[(d + 6) * 36 + rp] = (unsigned)y0.z | ((unsigned)y1.z << 16);
      Vt32[(d + 7) * 36 + rp] = (unsigned)y0.w | ((unsigned)y1.w << 16);
    }
  }

  const int p = lane & 15, g = lane >> 4;
  bf16x8_t qf[2][2];
  #pragma unroll
  for (int mt = 0; mt < 2; ++mt)
    #pragma unroll
    for (int ks = 0; ks < 2; ++ks)
      qf[mt][ks] = *reinterpret_cast<const bf16x8_t*>(
          base + (size_t)(l0 + mt * 16 + p) * (3 * E) + h * 64 + ks * 32 + g * 8);

  f32x4_t zero = {0.f, 0.f, 0.f, 0.f};
  f32x4_t accS[2][4];
  #pragma unroll
  for (int mt = 0; mt < 2; ++mt)
    #pragma unroll
    for (int nt = 0; nt < 4; ++nt) accS[mt][nt] = zero;
  #pragma unroll
  for (int ks = 0; ks < 2; ++ks) {
    bf16x8_t kf[4];
    #pragma unroll
    for (int nt = 0; nt < 4; ++nt) {
      int row = nt * 16 + p;
      int ba = (row * 128 + (ks * 32 + g * 8) * 2) ^ ((row & 7) << 4);
      kf[nt] = *reinterpret_cast<const bf16x8_t*>((char*)Klds + ba);
    }
    #pragma unroll
    for (int mt = 0; mt < 2; ++mt)
      #pragma unroll
      for (int nt = 0; nt < 4; ++nt)
        accS[mt][nt] = __builtin_amdgcn_mfma_f32_16x16x32_bf16(qf[mt][ks], kf[nt], accS[mt][nt], 0, 0, 0);
  }

  ushort_t* Plds = Klds;
  #pragma unroll
  for (int mt = 0; mt < 2; ++mt) {
    #pragma unroll
    for (int r = 0; r < 4; ++r) {
      int lq = l0 + mt * 16 + g * 4 + r;
      int st = lq - 16; st = st < 0 ? 0 : (st > LL - KS ? LL - KS : st);
      int clo = st - kb, chi = clo + 32;
      float sv[4];
      float mx = -1e30f;
      #pragma unroll
      for (int nt = 0; nt < 4; ++nt) {
        int c = nt * 16 + p;
        float s = accS[mt][nt][r] * 0.125f;
        s = (c >= clo && c <= chi) ? s : -1e30f;
        sv[nt] = s;
        mx = fmaxf(mx, s);
      }
      mx = fmaxf(mx, __shfl_xor(mx, 1));
      mx = fmaxf(mx, __shfl_xor(mx, 2));
      mx = fmaxf(mx, __shfl_xor(mx, 4));
      mx = fmaxf(mx, __shfl_xor(mx, 8));
      float sum = 0.f;
      #pragma unroll
      for (int nt = 0; nt < 4; ++nt) { float e = __expf(sv[nt] - mx); sv[nt] = e; sum += e; }
      sum += __shfl_xor(sum, 1);
      sum += __shfl_xor(sum, 2);
      sum += __shfl_xor(sum, 4);
      sum += __shfl_xor(sum, 8);
      float inv = 1.f / sum;
      int q = mt * 16 + g * 4 + r;
      #pragma unroll
      for (int nt = 0; nt < 4; ++nt)
        Plds[q * 72 + nt * 16 + p] = f2b(sv[nt] * inv);
    }
  }

  f32x4_t accO[2][4];
  #pragma unroll
  for (int mt = 0; mt < 2; ++mt)
    #pragma unroll
    for (int nt = 0; nt < 4; ++nt) accO[mt][nt] = zero;
  #pragma unroll
  for (int ks = 0; ks < 2; ++ks) {
    bf16x8_t pf[2], vf[4];
    #pragma unroll
    for (int mt = 0; mt < 2; ++mt)
      pf[mt] = *reinterpret_cast<const bf16x8_t*>(
          (char*)Plds + (mt * 16 + p) * 144 + (ks * 32 + g * 8) * 2);
    #pragma unroll
    for (int nt = 0; nt < 4; ++nt)
      vf[nt] = *reinterpret_cast<const bf16x8_t*>(
          (char*)Vt + (nt * 16 + p) * 144 + (ks * 32 + g * 8) * 2);
    #pragma unroll
    for (int mt = 0; mt < 2; ++mt)
      #pragma unroll
      for (int nt = 0; nt < 4; ++nt)
        accO[mt][nt] = __builtin_amdgcn_mfma_f32_16x16x32_bf16(pf[mt], vf[nt], accO[mt][nt], 0, 0, 0);
  }

  #pragma unroll
  for (int mt = 0; mt < 2; ++mt) {
    #pragma unroll
    for (int r = 0; r < 4; ++r) {
      int lq = l0 + mt * 16 + g * 4 + r;
      ushort_t* orow = out + ((size_t)(b * LL) + lq) * E + h * 64;
      #pragma unroll
      for (int nt = 0; nt < 4; ++nt)
        orow[nt * 16 + p] = f2b(accO[mt][nt][r]);
    }
  }
}

// ---------------- global MHA pieces (CLS query) ----------------
__global__ __launch_bounds__(256) void qcls_kernel(
    const ushort_t* __restrict__ xn, const float* __restrict__ inw,
    const float* __restrict__ inb, float* __restrict__ qcls)
{
  int i = blockIdx.x * 256 + threadIdx.x;
  int b = i >> 9, d = i & 511;
  const ushort_t* xr = xn + ((size_t)b * LP1 + LL) * E;
  const float* wr = inw + (size_t)d * E;
  float s = 0.f;
  for (int e = 0; e < E; e += 4) {
    ushort4 xv = *reinterpret_cast<const ushort4*>(xr + e);
    s += b2f(xv.x) * wr[e] + b2f(xv.y) * wr[e + 1] + b2f(xv.z) * wr[e + 2] + b2f(xv.w) * wr[e + 3];
  }
  qcls[i] = (s + inb[d]) * 0.125f;
}

// kv buffer layout: [NTOK][1024], K = cols 0..511, V = cols 512..1023
__global__ __launch_bounds__(256) void gscore_kernel(
    const float* __restrict__ qcls, const ushort_t* __restrict__ kv,
    float* __restrict__ sc)
{
  const int wav = blockIdx.x * 4 + (threadIdx.x >> 6);
  if (wav >= BB * LP1) return;
  const int lane = threadIdx.x & 63;
  const int b = wav / LP1, j = wav % LP1;
  const ushort_t* kr = kv + (size_t)wav * 1024 + lane * 8;
  const float* q = qcls + b * E + lane * 8;
  ushort4 ka = *reinterpret_cast<const ushort4*>(kr);
  ushort4 kb4 = *reinterpret_cast<const ushort4*>(kr + 4);
  float s = b2f(ka.x) * q[0] + b2f(ka.y) * q[1] + b2f(ka.z) * q[2] + b2f(ka.w) * q[3]
          + b2f(kb4.x) * q[4] + b2f(kb4.y) * q[5] + b2f(kb4.z) * q[6] + b2f(kb4.w) * q[7];
  s += __shfl_xor(s, 1); s += __shfl_xor(s, 2); s += __shfl_xor(s, 4);
  if ((lane & 7) == 0) sc[((size_t)(b * 8) + (lane >> 3)) * LP1 + j] = s;
}

__global__ __launch_bounds__(256) void gsoftmax_kernel(float* __restrict__ sc)
{
  float* row = sc + (size_t)blockIdx.x * LP1;
  __shared__ float sh[4];
  const int t = threadIdx.x;
  float m = -1e30f;
  for (int i = t; i < LP1; i += 256) m = fmaxf(m, row[i]);
  #pragma unroll
  for (int o = 32; o; o >>= 1) m = fmaxf(m, __shfl_xor(m, o));
  if ((t & 63) == 0) sh[t >> 6] = m;
  __syncthreads();
  m = fmaxf(fmaxf(sh[0], sh[1]), fmaxf(sh[2], sh[3]));
  __syncthreads();
  float s = 0.f;
  for (int i = t; i < LP1; i += 256) { float e = __expf(row[i] - m); row[i] = e; s += e; }
  #pragma unroll
  for (int o = 32; o; o >>= 1) s += __shfl_xor(s, o);
  if ((t & 63) == 0) sh[t >> 6] = s;
  __syncthreads();
  float inv = 1.f / (sh[0] + sh[1] + sh[2] + sh[3]);
  for (int i = t; i < LP1; i += 256) row[i] *= inv;
}

__global__ __launch_bounds__(256) void gpv_kernel(
    const float* __restrict__ sc, const ushort_t* __restrict__ kv,
    float* __restrict__ parts)
{
  __shared__ float red[4][64];
  const int bh = blockIdx.y;
  const int b = bh >> 3, h = bh & 7;
  const int c = blockIdx.x;
  const int lane = threadIdx.x & 63, s4 = threadIdx.x >> 6;
  const int j0 = c * 512;
  const int jend = (j0 + 512 < LP1) ? j0 + 512 : LP1;
  const float* prow = sc + (size_t)bh * LP1;
  const ushort_t* vbase = kv + (size_t)b * LP1 * 1024 + 512 + h * 64 + lane;
  float acc = 0.f;
  for (int j = j0 + s4; j < jend; j += 4)
    acc += prow[j] * b2f(vbase[(size_t)j * 1024]);
  red[s4][lane] = acc;
  __syncthreads();
  if (s4 == 0)
    parts[((size_t)c * 16 + bh) * 64 + lane] = red[0][lane] + red[1][lane] + red[2][lane] + red[3][lane];
}

__global__ void gpv_reduce(const float* __restrict__ parts, float* __restrict__ oc)
{
  int i = blockIdx.x * 256 + threadIdx.x;
  if (i < BB * E) {
    float s = 0.f;
    #pragma unroll
    for (int c = 0; c < 9; ++c) s += parts[c * 1024 + i];
    oc[i] = s;
  }
}

__global__ __launch_bounds__(256) void xcls_kernel(
    const float* __restrict__ oc, const float* __restrict__ ow,
    const float* __restrict__ ob, float* __restrict__ xc)
{
  int i = blockIdx.x * 256 + threadIdx.x;
  if (i >= BB * E) return;
  int b = i >> 9, n = i & 511;
  const float* o = oc + b * E;
  const float* wr = ow + (size_t)n * E;
  float s = ob[n];
  for (int m = 0; m < E; ++m) s += o[m] * wr[m];
  xc[i] = s;
}

// ---------------- fused fp32 -> bf16 weight convert (all 5 weights) ----------------
__global__ void cvt_all(
    const float* __restrict__ s0, ushort_t* __restrict__ d0, int n0,
    const float* __restrict__ s1, ushort_t* __restrict__ d1, int n1,
    const float* __restrict__ s2, ushort_t* __restrict__ d2, int n2,
    const float* __restrict__ s3, ushort_t* __restrict__ d3, int n3,
    const float* __restrict__ s4, ushort_t* __restrict__ d4, int n4)
{
  int i = (blockIdx.x * 256 + threadIdx.x) * 4;
  const float* s; ushort_t* d;
  if (i < n0)                { s = s0; d = d0; }
  else if ((i -= n0) < n1)   { s = s1; d = d1; }
  else if ((i -= n1) < n2)   { s = s2; d = d2; }
  else if ((i -= n2) < n3)   { s = s3; d = d3; }
  else if ((i -= n3) < n4)   { s = s4; d = d4; }
  else return;
  float4 v = *reinterpret_cast<const float4*>(s + i);
  ushort4 o;
  o.x = f2b(v.x); o.y = f2b(v.y); o.z = f2b(v.z); o.w = f2b(v.w);
  *reinterpret_cast<ushort4*>(d + i) = o;
}

// ---------------- launch ----------------
extern "C" void kernel_launch(void* const* d_in, const int* in_sizes, int n_in,
                              void* d_out, int out_size, void* d_ws, size_t ws_size,
                              hipStream_t stream)
{
  const float* x      = (const float*)d_in[0];
  const float* ln1_g  = (const float*)d_in[1];
  const float* ln1_b  = (const float*)d_in[2];
  const float* qkv_w  = (const float*)d_in[3];
  const float* qkv_b  = (const float*)d_in[4];
  const float* na_w   = (const float*)d_in[5];
  const float* na_b   = (const float*)d_in[6];
  const float* in_w   = (const float*)d_in[7];
  const float* in_b   = (const float*)d_in[8];
  const float* out_w  = (const float*)d_in[9];
  const float* out_b  = (const float*)d_in[10];
  const float* ln2_g  = (const float*)d_in[11];
  const float* ln2_b  = (const float*)d_in[12];
  const float* fc1_w  = (const float*)d_in[13];
  const float* fc1_b  = (const float*)d_in[14];
  const float* fc2_w  = (const float*)d_in[15];
  const float* fc2_b  = (const float*)d_in[16];
  float* out = (float*)d_out;

  char* pws = (char*)d_ws;
  size_t off = 0;
  auto alloc = [&](size_t bytes) {
    void* r = pws + off; off = (off + bytes + 255) & ~(size_t)255; return r;
  };
  ushort_t* w_qkv = (ushort_t*)alloc((size_t)3 * E * E * 2);
  ushort_t* w_na  = (ushort_t*)alloc((size_t)E * E * 2);
  ushort_t* w_in  = (ushort_t*)alloc((size_t)3 * E * E * 2);
  ushort_t* w_fc1 = (ushort_t*)alloc((size_t)FDIM * E * 2);
  ushort_t* w_fc2 = (ushort_t*)alloc((size_t)E * FDIM * 2);
  ushort_t* xn1   = (ushort_t*)alloc((size_t)NTOK * E * 2);     // reused as xn2
  char*     bigR  = (char*)alloc((size_t)NTOK * FDIM * 2);      // phase-shared region
  ushort_t* qkvb  = (ushort_t*)bigR;                            // phase A: qkv
  ushort_t* natt  = (ushort_t*)(bigR + (size_t)NLOC * 3 * E * 2); // phase A: natten out
  ushort_t* kvg   = (ushort_t*)bigR;                            // phase B: fused K|V [NTOK][1024]
  ushort_t* hbuf  = (ushort_t*)bigR;                            // phase C: MLP hidden
  ushort_t* tmpk  = (ushort_t*)alloc((size_t)NTOK * E * 2);
  float*    sc    = (float*)alloc((size_t)BB * H * LP1 * 4);
  float*    qcls  = (float*)alloc(1024 * 4);
  float*    parts = (float*)alloc(9 * 16 * 64 * 4);
  float*    oc    = (float*)alloc(1024 * 4);
  float*    xcls  = (float*)alloc(1024 * 4);
  float*    xa    = (float*)alloc((size_t)NTOK * E * 4);
  ushort_t* xn2   = xn1;
  // split-K partial (fp32, NTOK x E) -- only if workspace allows
  size_t off_before_s0 = off;
  float*    s0    = (float*)alloc((size_t)NTOK * E * 4);
  const bool can_split = (off <= ws_size);
  if (!can_split) off = off_before_s0;

  // fused weight converts
  cvt_all<<<3840, 256, 0, stream>>>(
      qkv_w, w_qkv, 3 * E * E,
      na_w,  w_na,  E * E,
      in_w,  w_in,  3 * E * E,
      fc1_w, w_fc1, FDIM * E,
      fc2_w, w_fc2, E * FDIM);

  // LN1 (+ tmp_key cls rows)
  ln_fused1<<<NTOK, 256, 0, stream>>>(x, ln1_g, ln1_b, xn1, tmpk);
  // CLS query projection
  qcls_kernel<<<4, 256, 0, stream>>>(xn1, in_w, in_b, qcls);
  // QKV for local tokens
  gemm_bt<128,0,0,0,1,0,0><<<dim3(NLOC / BM, 3 * E / 128), 256, 0, stream>>>(
      xn1, w_qkv, qkv_b, nullptr, qkvb, nullptr, NLOC, 3 * E, E, E);
  // neighborhood attention (MFMA)
  natten_mfma<<<512, 256, 0, stream>>>(qkvb, natt);
  // output projection -> tmp_key rows
  gemm_bt<128,0,0,0,0,1,0><<<dim3(NLOC / BM, E / 128), 256, 0, stream>>>(
      natt, w_na, na_b, nullptr, tmpk, nullptr, NLOC, E, E, E);
  // fused global K+V projection (rows E..3E of in_w are contiguous)
  gemm_bt<128,0,0,0,0,0,0><<<dim3((NTOK + BM - 1) / BM, 1024 / 128), 256, 0, stream>>>(
      tmpk, w_in + (size_t)E * E, in_b + E, nullptr, kvg, nullptr, NTOK, 1024, E, E);
  // CLS attention
  gscore_kernel<<<(BB * LP1 + 3) / 4, 256, 0, stream>>>(qcls, kvg, sc);
  gsoftmax_kernel<<<BB * H, 256, 0, stream>>>(sc);
  gpv_kernel<<<dim3(9, BB * H), 256, 0, stream>>>(sc, kvg, parts);
  gpv_reduce<<<4, 256, 0, stream>>>(parts, oc);
  xcls_kernel<<<4, 256, 0, stream>>>(oc, out_w, out_b, xcls);
  // residual + LN2
  resid_ln2<<<NTOK, 256, 0, stream>>>(x, tmpk, xcls, ln2_g, ln2_b, xa, xn2);
  // MLP
  gemm_bt<128,1,0,0,0,0,0><<<dim3((NTOK + BM - 1) / BM, FDIM / 128), 256, 0, stream>>>(
      xn2, w_fc1, fc1_b, nullptr, hbuf, nullptr, NTOK, FDIM, E, E);
  if (can_split) {
    // fc2 split-K=2, BN=64: z=0 -> s0 (raw), z=1 -> out (raw); then reduce
    gemm_bt<64,0,0,0,0,0,1><<<dim3((NTOK + BM - 1) / BM, E / 64, 2), 256, 0, stream>>>(
        hbuf, w_fc2, fc2_b, s0, (ushort_t*)out, nullptr, NTOK, E, FDIM, FDIM / 2);
    fc2_reduce<<<(NTOK * E / 4) / 256, 256, 0, stream>>>(out, s0, fc2_b, xa);
  } else {
    gemm_bt<64,0,1,1,0,0,0><<<dim3((NTOK + BM - 1) / BM, E / 64), 256, 0, stream>>>(
        hbuf, w_fc2, fc2_b, out, nullptr, xa, NTOK, E, FDIM, FDIM);
  }
}

// Round 4
// 280.673 us; speedup vs baseline: 1.3056x; 1.0244x over previous
//
#include <hip/hip_runtime.h>
#include <hip/hip_bf16.h>
#include <cstdint>
#include <cstddef>

// ---------------- problem constants ----------------
#define E    512
#define H    8
#define DHD  64
#define FDIM 2048
#define KS   33
#define BB   2
#define LL   4096
#define LP1  4097
#define NTOK 8194   // BB*LP1
#define NLOC 8192   // BB*LL

typedef unsigned short ushort_t;
typedef __bf16 bf16x8_t __attribute__((ext_vector_type(8)));
typedef float  f32x4_t  __attribute__((ext_vector_type(4)));

__device__ __forceinline__ float b2f(unsigned short h) {
  union { unsigned int u; float f; } un; un.u = ((unsigned int)h) << 16; return un.f;
}
__device__ __forceinline__ unsigned short f2b(float f) {
  union { float f; unsigned int u; } un; un.f = f;
  unsigned int u = un.u;
  return (unsigned short)((u + 0x7FFFu + ((u >> 16) & 1u)) >> 16);
}

__device__ __forceinline__ void gload16(const ushort_t* g, ushort_t* l) {
  __builtin_amdgcn_global_load_lds(
      (const __attribute__((address_space(1))) void*)g,
      (__attribute__((address_space(3))) void*)l,
      16, 0, 0);
}

// m204 bijective XCD chunk remap: hw id (round-robin xcd = hw%8) -> logical id
// such that each XCD owns a contiguous logical chunk.
__device__ __forceinline__ int xcd_remap(int hw, int n) {
  int xcd = hw & 7, j = hw >> 3;
  int q = n >> 3, r = n & 7;
  return (xcd < r ? xcd * (q + 1) : r * (q + 1) + (xcd - r) * q) + j;
}

// ---------------- bf16 MFMA GEMM:  C = A(MxK) @ W(NxK)^T + bias ----------------
// BK=64 (128B LDS rows), XOR-swizzled (slot ^= row&7) with pre-swizzled global
// source (rule #21). 4 waves 2x2. 2-phase double-buffered K-loop: STAGE(next)
// overlaps compute(cur); ONE __syncthreads per K-step (its vmcnt(0) is the
// drain). 1-D grid with XCD remap, decode (x outer, z, y inner) so each XCD
// keeps its A-panel + full W L2-resident.
#define BM 128

template<int BNT, int ACT, int OUTF, int ADDRES, int INRM, int OUTRM, int PARTIAL>
__global__ __launch_bounds__(256) void gemm_bt(
    const ushort_t* __restrict__ A, const ushort_t* __restrict__ W,
    const float* __restrict__ bias, float* __restrict__ outF,
    ushort_t* __restrict__ outB, const float* __restrict__ res,
    int M, int N, int K, int klen, int ny, int nz)
{
  constexpr int NFRAG = BNT / 32;          // n-fragments per wave (4 or 2)
  __shared__ ushort_t Alds[2][BM * 64];
  __shared__ ushort_t Blds[2][BNT * 64];
  const int t    = threadIdx.x;
  const int lane = t & 63;
  const int w    = t >> 6;
  const int wr   = w >> 1, wc = w & 1;

  const int Lid = xcd_remap(blockIdx.x, gridDim.x);
  const int bx  = Lid / (ny * nz);
  const int rem = Lid % (ny * nz);
  const int z   = rem / ny;
  const int by  = rem % ny;
  const int bmBase = bx * BM;
  const int bnBase = by * BNT;
  const int kbeg = z * klen;

  f32x4_t zero = {0.f, 0.f, 0.f, 0.f};
  f32x4_t acc[4][NFRAG];
  #pragma unroll
  for (int m = 0; m < 4; ++m)
    #pragma unroll
    for (int n = 0; n < NFRAG; ++n) acc[m][n] = zero;

  // staging map: chunk c = round*256+t -> row=c>>3, slot j=t&7 (16B chunks);
  // slot j holds logical k-chunk j^(row&7); row&7 == (t>>3)&7 for all rounds.
  const int srow = t >> 3;                 // 0..31
  const int jsw8 = ((t & 7) ^ (srow & 7)) * 8;   // pre-swizzled k-offset (elems)
  int arow[4];
  #pragma unroll
  for (int r = 0; r < 4; ++r) {
    int rr = bmBase + r * 32 + srow;
    if (INRM) rr += rr >> 12;              // local row -> padded row (skip cls)
    else if (rr >= M) rr = M - 1;
    arow[r] = rr;
  }
  int brow[NFRAG];
  #pragma unroll
  for (int r = 0; r < NFRAG; ++r) brow[r] = bnBase + r * 32 + srow;

  const int frow = lane & 15;
  const int g    = lane >> 4;

  auto STAGE = [&](int s, int k0) {
    #pragma unroll
    for (int r = 0; r < 4; ++r)
      gload16(A + (size_t)arow[r] * K + k0 + jsw8, &Alds[s][(size_t)(r * 256 + t) * 8]);
    #pragma unroll
    for (int r = 0; r < NFRAG; ++r)
      gload16(W + (size_t)brow[r] * K + k0 + jsw8, &Blds[s][(size_t)(r * 256 + t) * 8]);
  };

  const int nt = klen >> 6;
  STAGE(0, kbeg);
  __syncthreads();

  for (int it = 0; it < nt; ++it) {
    const int cur = it & 1;
    // ds_read all fragments of current tile
    bf16x8_t af[2][4], bfv[2][NFRAG];
    #pragma unroll
    for (int kk2 = 0; kk2 < 2; ++kk2) {
      const int kosw = ((kk2 * 4 + g) ^ (frow & 7)) << 4;
      #pragma unroll
      for (int m = 0; m < 4; ++m) {
        int row = wr * 64 + m * 16 + frow;
        af[kk2][m] = *reinterpret_cast<const bf16x8_t*>((char*)Alds[cur] + row * 128 + kosw);
      }
      #pragma unroll
      for (int n = 0; n < NFRAG; ++n) {
        int row = wc * (BNT / 2) + n * 16 + frow;
        bfv[kk2][n] = *reinterpret_cast<const bf16x8_t*>((char*)Blds[cur] + row * 128 + kosw);
      }
    }
    // issue next-tile staging while MFMAs run; the __syncthreads below drains it
    if (it + 1 < nt) STAGE(cur ^ 1, kbeg + (it + 1) * 64);
    #pragma unroll
    for (int kk2 = 0; kk2 < 2; ++kk2)
      #pragma unroll
      for (int m = 0; m < 4; ++m)
        #pragma unroll
        for (int n = 0; n < NFRAG; ++n)
          acc[m][n] = __builtin_amdgcn_mfma_f32_16x16x32_bf16(af[kk2][m], bfv[kk2][n], acc[m][n], 0, 0, 0);
    __syncthreads();
  }

  // epilogue: C/D layout col=lane&15, row=(lane>>4)*4+r
  const int rbase = g * 4;
  const int cbase = frow;
  float* po = nullptr;
  if (PARTIAL) po = (z == 0) ? outF : (float*)outB;
  #pragma unroll
  for (int m = 0; m < 4; ++m) {
    #pragma unroll
    for (int r = 0; r < 4; ++r) {
      int gr = bmBase + wr * 64 + m * 16 + rbase + r;
      if (gr < M) {
        int orow = OUTRM ? gr + (gr >> 12) : gr;
        #pragma unroll
        for (int n = 0; n < NFRAG; ++n) {
          int gc = bnBase + wc * (BNT / 2) + n * 16 + cbase;
          float v = acc[m][n][r];
          if (PARTIAL) {
            po[(size_t)orow * N + gc] = v;
          } else {
            v += bias[gc];
            if (ACT == 1) v = v / (1.f + __expf(-v));
            if (ADDRES) v += res[(size_t)gr * N + gc];
            if (OUTF) outF[(size_t)orow * N + gc] = v;
            else      outB[(size_t)orow * N + gc] = f2b(v);
          }
        }
      }
    }
  }
}

// ---------------- split-K reduce: out = out(P1) + P0 + bias + xa ----------------
__global__ __launch_bounds__(256) void fc2_reduce(
    float* __restrict__ out, const float* __restrict__ p0,
    const float* __restrict__ bias, const float* __restrict__ xa)
{
  size_t i = (size_t)blockIdx.x * 256 + threadIdx.x;   // float4 index
  float4 o = reinterpret_cast<const float4*>(out)[i];
  float4 a = reinterpret_cast<const float4*>(p0)[i];
  float4 x = reinterpret_cast<const float4*>(xa)[i];
  float4 bcol = reinterpret_cast<const float4*>(bias)[i & 127];
  o.x += a.x + x.x + bcol.x;
  o.y += a.y + x.y + bcol.y;
  o.z += a.z + x.z + bcol.z;
  o.w += a.w + x.w + bcol.w;
  reinterpret_cast<float4*>(out)[i] = o;
}

// ---------------- LN1 (also copies cls rows into tmp_key) ----------------
__global__ __launch_bounds__(256) void ln_fused1(
    const float* __restrict__ x, const float* __restrict__ g,
    const float* __restrict__ be, ushort_t* __restrict__ xn,
    ushort_t* __restrict__ tmpk)
{
  __shared__ float sh[4];
  const int row = blockIdx.x;
  const int t = threadIdx.x;
  const float* xr = x + (size_t)row * E;
  float v0 = xr[t], v1 = xr[t + 256];
  float sum = v0 + v1;
  #pragma unroll
  for (int o = 32; o; o >>= 1) sum += __shfl_xor(sum, o);
  if ((t & 63) == 0) sh[t >> 6] = sum;
  __syncthreads();
  float mean = (sh[0] + sh[1] + sh[2] + sh[3]) * (1.f / E);
  __syncthreads();
  float d0 = v0 - mean, d1 = v1 - mean;
  float vs = d0 * d0 + d1 * d1;
  #pragma unroll
  for (int o = 32; o; o >>= 1) vs += __shfl_xor(vs, o);
  if ((t & 63) == 0) sh[t >> 6] = vs;
  __syncthreads();
  float var = (sh[0] + sh[1] + sh[2] + sh[3]) * (1.f / E);
  float rstd = rsqrtf(var + 1e-5f);
  unsigned short o0 = f2b(d0 * rstd * g[t] + be[t]);
  unsigned short o1 = f2b(d1 * rstd * g[t + 256] + be[t + 256]);
  xn[(size_t)row * E + t] = o0;
  xn[(size_t)row * E + t + 256] = o1;
  if ((row % LP1) == LL) {
    tmpk[(size_t)row * E + t] = o0;
    tmpk[(size_t)row * E + t + 256] = o1;
  }
}

// ---------------- residual-add + LN2 ----------------
__global__ __launch_bounds__(256) void resid_ln2(
    const float* __restrict__ x, const ushort_t* __restrict__ tmpk,
    const float* __restrict__ xcls, const float* __restrict__ g,
    const float* __restrict__ be, float* __restrict__ xa,
    ushort_t* __restrict__ xn2)
{
  __shared__ float sh[4];
  const int row = blockIdx.x;
  const int b = row / LP1, l = row % LP1;
  const int t = threadIdx.x;
  float a0, a1;
  if (l < LL) { a0 = b2f(tmpk[(size_t)row * E + t]); a1 = b2f(tmpk[(size_t)row * E + t + 256]); }
  else        { a0 = xcls[b * E + t];                a1 = xcls[b * E + t + 256]; }
  float v0 = x[(size_t)row * E + t] + a0;
  float v1 = x[(size_t)row * E + t + 256] + a1;
  xa[(size_t)row * E + t] = v0;
  xa[(size_t)row * E + t + 256] = v1;
  float sum = v0 + v1;
  #pragma unroll
  for (int o = 32; o; o >>= 1) sum += __shfl_xor(sum, o);
  if ((t & 63) == 0) sh[t >> 6] = sum;
  __syncthreads();
  float mean = (sh[0] + sh[1] + sh[2] + sh[3]) * (1.f / E);
  __syncthreads();
  float d0 = v0 - mean, d1 = v1 - mean;
  float vs = d0 * d0 + d1 * d1;
  #pragma unroll
  for (int o = 32; o; o >>= 1) vs += __shfl_xor(vs, o);
  if ((t & 63) == 0) sh[t >> 6] = vs;
  __syncthreads();
  float var = (sh[0] + sh[1] + sh[2] + sh[3]) * (1.f / E);
  float rstd = rsqrtf(var + 1e-5f);
  xn2[(size_t)row * E + t]       = f2b(d0 * rstd * g[t] + be[t]);
  xn2[(size_t)row * E + t + 256] = f2b(d1 * rstd * g[t + 256] + be[t + 256]);
}

// ---------------- neighborhood attention via MFMA ----------------
__global__ __launch_bounds__(256) void natten_mfma(
    const ushort_t* __restrict__ qkv, ushort_t* __restrict__ out)
{
  __shared__ ushort_t KP[4][64 * 64];   // K tile (XOR-swizzled); reused for P [32][72]
  __shared__ ushort_t VT[4][64 * 72];   // V^T, stride 72 elems
  const int w    = threadIdx.x >> 6;
  const int lane = threadIdx.x & 63;
  const int task = blockIdx.x * 4 + w;
  const int h  = task & 7;
  const int qb = (task >> 3) & 127;
  const int b  = task >> 10;
  const int l0 = qb * 32;
  const int kb = l0 - 16;
  const ushort_t* base = qkv + (size_t)b * LL * (3 * E);
  ushort_t* Klds = KP[w];
  ushort_t* Vt   = VT[w];

  {
    const int rsub = lane >> 3;
    const int d0   = (lane & 7) * 8;
    #pragma unroll
    for (int i = 0; i < 8; ++i) {
      int row = i * 8 + rsub;
      int gl = kb + row; gl = gl < 0 ? 0 : (gl > LL - 1 ? LL - 1 : gl);
      bf16x8_t kv = *reinterpret_cast<const bf16x8_t*>(
          base + (size_t)gl * (3 * E) + E + h * 64 + d0);
      int ba = (row * 128 + d0 * 2) ^ ((row & 7) << 4);
      *reinterpret_cast<bf16x8_t*>((char*)Klds + ba) = kv;
    }
  }
  {
    const int a  = lane & 7;
    const int c8 = lane >> 3;
    unsigned int* Vt32 = (unsigned int*)Vt;
    #pragma unroll
    for (int i = 0; i < 4; ++i) {
      int rp = i * 8 + c8;
      int g0 = kb + rp * 2;     g0 = g0 < 0 ? 0 : (g0 > LL - 1 ? LL - 1 : g0);
      int g1 = kb + rp * 2 + 1; g1 = g1 < 0 ? 0 : (g1 > LL - 1 ? LL - 1 : g1);
      const ushort_t* v0 = base + (size_t)g0 * (3 * E) + 2 * E + h * 64 + a * 8;
      const ushort_t* v1 = base + (size_t)g1 * (3 * E) + 2 * E + h * 64 + a * 8;
      ushort4 x0 = *(const ushort4*)v0,       x1 = *(const ushort4*)v1;
      ushort4 y0 = *(const ushort4*)(v0 + 4), y1 = *(const ushort4*)(v1 + 4);
      int d = a * 8;
      Vt32[(d + 0) * 36 + rp] = (unsigned)x0.x | ((unsigned)x1.x << 16);
      Vt32[(d + 1) * 36 + rp] = (unsigned)x0.y | ((unsigned)x1.y << 16);
      Vt32[(d + 2) * 36 + rp] = (unsigned)x0.z | ((unsigned)x1.z << 16);
      Vt32[(d + 3) * 36 + rp] = (unsigned)x0.w | ((unsigned)x1.w << 16);
      Vt32[(d + 4) * 36 + rp] = (unsigned)y0.x | ((unsigned)y1.x << 16);
      Vt32[(d + 5) * 36 + rp] = (unsigned)y0.y | ((unsigned)y1.y << 16);
      Vt32[(d + 6) * 36 + rp] = (unsigned)y0.z | ((unsigned)y1.z << 16);
      Vt32[(d + 7) * 36 + rp] = (unsigned)y0.w | ((unsigned)y1.w << 16);
    }
  }

  const int p = lane & 15, g = lane >> 4;
  bf16x8_t qf[2][2];
  #pragma unroll
  for (int mt = 0; mt < 2; ++mt)
    #pragma unroll
    for (int ks = 0; ks < 2; ++ks)
      qf[mt][ks] = *reinterpret_cast<const bf16x8_t*>(
          base + (size_t)(l0 + mt * 16 + p) * (3 * E) + h * 64 + ks * 32 + g * 8);

  f32x4_t zero = {0.f, 0.f, 0.f, 0.f};
  f32x4_t accS[2][4];
  #pragma unroll
  for (int mt = 0; mt < 2; ++mt)
    #pragma unroll
    for (int nt = 0; nt < 4; ++nt) accS[mt][nt] = zero;
  #pragma unroll
  for (int ks = 0; ks < 2; ++ks) {
    bf16x8_t kf[4];
    #pragma unroll
    for (int nt = 0; nt < 4; ++nt) {
      int row = nt * 16 + p;
      int ba = (row * 128 + (ks * 32 + g * 8) * 2) ^ ((row & 7) << 4);
      kf[nt] = *reinterpret_cast<const bf16x8_t*>((char*)Klds + ba);
    }
    #pragma unroll
    for (int mt = 0; mt < 2; ++mt)
      #pragma unroll
      for (int nt = 0; nt < 4; ++nt)
        accS[mt][nt] = __builtin_amdgcn_mfma_f32_16x16x32_bf16(qf[mt][ks], kf[nt], accS[mt][nt], 0, 0, 0);
  }

  ushort_t* Plds = Klds;
  #pragma unroll
  for (int mt = 0; mt < 2; ++mt) {
    #pragma unroll
    for (int r = 0; r < 4; ++r) {
      int lq = l0 + mt * 16 + g * 4 + r;
      int st = lq - 16; st = st < 0 ? 0 : (st > LL - KS ? LL - KS : st);
      int clo = st - kb, chi = clo + 32;
      float sv[4];
      float mx = -1e30f;
      #pragma unroll
      for (int nt = 0; nt < 4; ++nt) {
        int c = nt * 16 + p;
        float s = accS[mt][nt][r] * 0.125f;
        s = (c >= clo && c <= chi) ? s : -1e30f;
        sv[nt] = s;
        mx = fmaxf(mx, s);
      }
      mx = fmaxf(mx, __shfl_xor(mx, 1));
      mx = fmaxf(mx, __shfl_xor(mx, 2));
      mx = fmaxf(mx, __shfl_xor(mx, 4));
      mx = fmaxf(mx, __shfl_xor(mx, 8));
      float sum = 0.f;
      #pragma unroll
      for (int nt = 0; nt < 4; ++nt) { float e = __expf(sv[nt] - mx); sv[nt] = e; sum += e; }
      sum += __shfl_xor(sum, 1);
      sum += __shfl_xor(sum, 2);
      sum += __shfl_xor(sum, 4);
      sum += __shfl_xor(sum, 8);
      float inv = 1.f / sum;
      int q = mt * 16 + g * 4 + r;
      #pragma unroll
      for (int nt = 0; nt < 4; ++nt)
        Plds[q * 72 + nt * 16 + p] = f2b(sv[nt] * inv);
    }
  }

  f32x4_t accO[2][4];
  #pragma unroll
  for (int mt = 0; mt < 2; ++mt)
    #pragma unroll
    for (int nt = 0; nt < 4; ++nt) accO[mt][nt] = zero;
  #pragma unroll
  for (int ks = 0; ks < 2; ++ks) {
    bf16x8_t pf[2], vf[4];
    #pragma unroll
    for (int mt = 0; mt < 2; ++mt)
      pf[mt] = *reinterpret_cast<const bf16x8_t*>(
          (char*)Plds + (mt * 16 + p) * 144 + (ks * 32 + g * 8) * 2);
    #pragma unroll
    for (int nt = 0; nt < 4; ++nt)
      vf[nt] = *reinterpret_cast<const bf16x8_t*>(
          (char*)Vt + (nt * 16 + p) * 144 + (ks * 32 + g * 8) * 2);
    #pragma unroll
    for (int mt = 0; mt < 2; ++mt)
      #pragma unroll
      for (int nt = 0; nt < 4; ++nt)
        accO[mt][nt] = __builtin_amdgcn_mfma_f32_16x16x32_bf16(pf[mt], vf[nt], accO[mt][nt], 0, 0, 0);
  }

  #pragma unroll
  for (int mt = 0; mt < 2; ++mt) {
    #pragma unroll
    for (int r = 0; r < 4; ++r) {
      int lq = l0 + mt * 16 + g * 4 + r;
      ushort_t* orow = out + ((size_t)(b * LL) + lq) * E + h * 64;
      #pragma unroll
      for (int nt = 0; nt < 4; ++nt)
        orow[nt * 16 + p] = f2b(accO[mt][nt][r]);
    }
  }
}

// ---------------- global MHA pieces (CLS query) ----------------
__global__ __launch_bounds__(256) void qcls_kernel(
    const ushort_t* __restrict__ xn, const float* __restrict__ inw,
    const float* __restrict__ inb, float* __restrict__ qcls)
{
  int i = blockIdx.x * 256 + threadIdx.x;
  int b = i >> 9, d = i & 511;
  const ushort_t* xr = xn + ((size_t)b * LP1 + LL) * E;
  const float* wr = inw + (size_t)d * E;
  float s = 0.f;
  for (int e = 0; e < E; e += 4) {
    ushort4 xv = *reinterpret_cast<const ushort4*>(xr + e);
    s += b2f(xv.x) * wr[e] + b2f(xv.y) * wr[e + 1] + b2f(xv.z) * wr[e + 2] + b2f(xv.w) * wr[e + 3];
  }
  qcls[i] = (s + inb[d]) * 0.125f;
}

// kv buffer layout: [NTOK][1024], K = cols 0..511, V = cols 512..1023
__global__ __launch_bounds__(256) void gscore_kernel(
    const float* __restrict__ qcls, const ushort_t* __restrict__ kv,
    float* __restrict__ sc)
{
  const int wav = blockIdx.x * 4 + (threadIdx.x >> 6);
  if (wav >= BB * LP1) return;
  const int lane = threadIdx.x & 63;
  const int b = wav / LP1, j = wav % LP1;
  const ushort_t* kr = kv + (size_t)wav * 1024 + lane * 8;
  const float* q = qcls + b * E + lane * 8;
  ushort4 ka = *reinterpret_cast<const ushort4*>(kr);
  ushort4 kb4 = *reinterpret_cast<const ushort4*>(kr + 4);
  float s = b2f(ka.x) * q[0] + b2f(ka.y) * q[1] + b2f(ka.z) * q[2] + b2f(ka.w) * q[3]
          + b2f(kb4.x) * q[4] + b2f(kb4.y) * q[5] + b2f(kb4.z) * q[6] + b2f(kb4.w) * q[7];
  s += __shfl_xor(s, 1); s += __shfl_xor(s, 2); s += __shfl_xor(s, 4);
  if ((lane & 7) == 0) sc[((size_t)(b * 8) + (lane >> 3)) * LP1 + j] = s;
}

__global__ __launch_bounds__(256) void gsoftmax_kernel(float* __restrict__ sc)
{
  float* row = sc + (size_t)blockIdx.x * LP1;
  __shared__ float sh[4];
  const int t = threadIdx.x;
  float m = -1e30f;
  for (int i = t; i < LP1; i += 256) m = fmaxf(m, row[i]);
  #pragma unroll
  for (int o = 32; o; o >>= 1) m = fmaxf(m, __shfl_xor(m, o));
  if ((t & 63) == 0) sh[t >> 6] = m;
  __syncthreads();
  m = fmaxf(fmaxf(sh[0], sh[1]), fmaxf(sh[2], sh[3]));
  __syncthreads();
  float s = 0.f;
  for (int i = t; i < LP1; i += 256) { float e = __expf(row[i] - m); row[i] = e; s += e; }
  #pragma unroll
  for (int o = 32; o; o >>= 1) s += __shfl_xor(s, o);
  if ((t & 63) == 0) sh[t >> 6] = s;
  __syncthreads();
  float inv = 1.f / (sh[0] + sh[1] + sh[2] + sh[3]);
  for (int i = t; i < LP1; i += 256) row[i] *= inv;
}

__global__ __launch_bounds__(256) void gpv_kernel(
    const float* __restrict__ sc, const ushort_t* __restrict__ kv,
    float* __restrict__ parts)
{
  __shared__ float red[4][64];
  const int bh = blockIdx.y;
  const int b = bh >> 3, h = bh & 7;
  const int c = blockIdx.x;
  const int lane = threadIdx.x & 63, s4 = threadIdx.x >> 6;
  const int j0 = c * 512;
  const int jend = (j0 + 512 < LP1) ? j0 + 512 : LP1;
  const float* prow = sc + (size_t)bh * LP1;
  const ushort_t* vbase = kv + (size_t)b * LP1 * 1024 + 512 + h * 64 + lane;
  float acc = 0.f;
  for (int j = j0 + s4; j < jend; j += 4)
    acc += prow[j] * b2f(vbase[(size_t)j * 1024]);
  red[s4][lane] = acc;
  __syncthreads();
  if (s4 == 0)
    parts[((size_t)c * 16 + bh) * 64 + lane] = red[0][lane] + red[1][lane] + red[2][lane] + red[3][lane];
}

__global__ void gpv_reduce(const float* __restrict__ parts, float* __restrict__ oc)
{
  int i = blockIdx.x * 256 + threadIdx.x;
  if (i < BB * E) {
    float s = 0.f;
    #pragma unroll
    for (int c = 0; c < 9; ++c) s += parts[c * 1024 + i];
    oc[i] = s;
  }
}

__global__ __launch_bounds__(256) void xcls_kernel(
    const float* __restrict__ oc, const float* __restrict__ ow,
    const float* __restrict__ ob, float* __restrict__ xc)
{
  int i = blockIdx.x * 256 + threadIdx.x;
  if (i >= BB * E) return;
  int b = i >> 9, n = i & 511;
  const float* o = oc + b * E;
  const float* wr = ow + (size_t)n * E;
  float s = ob[n];
  for (int m = 0; m < E; ++m) s += o[m] * wr[m];
  xc[i] = s;
}

// ---------------- fused fp32 -> bf16 weight convert (all 5 weights) ----------------
__global__ void cvt_all(
    const float* __restrict__ s0, ushort_t* __restrict__ d0, int n0,
    const float* __restrict__ s1, ushort_t* __restrict__ d1, int n1,
    const float* __restrict__ s2, ushort_t* __restrict__ d2, int n2,
    const float* __restrict__ s3, ushort_t* __restrict__ d3, int n3,
    const float* __restrict__ s4, ushort_t* __restrict__ d4, int n4)
{
  int i = (blockIdx.x * 256 + threadIdx.x) * 4;
  const float* s; ushort_t* d;
  if (i < n0)                { s = s0; d = d0; }
  else if ((i -= n0) < n1)   { s = s1; d = d1; }
  else if ((i -= n1) < n2)   { s = s2; d = d2; }
  else if ((i -= n2) < n3)   { s = s3; d = d3; }
  else if ((i -= n3) < n4)   { s = s4; d = d4; }
  else return;
  float4 v = *reinterpret_cast<const float4*>(s + i);
  ushort4 o;
  o.x = f2b(v.x); o.y = f2b(v.y); o.z = f2b(v.z); o.w = f2b(v.w);
  *reinterpret_cast<ushort4*>(d + i) = o;
}

// ---------------- launch ----------------
extern "C" void kernel_launch(void* const* d_in, const int* in_sizes, int n_in,
                              void* d_out, int out_size, void* d_ws, size_t ws_size,
                              hipStream_t stream)
{
  const float* x      = (const float*)d_in[0];
  const float* ln1_g  = (const float*)d_in[1];
  const float* ln1_b  = (const float*)d_in[2];
  const float* qkv_w  = (const float*)d_in[3];
  const float* qkv_b  = (const float*)d_in[4];
  const float* na_w   = (const float*)d_in[5];
  const float* na_b   = (const float*)d_in[6];
  const float* in_w   = (const float*)d_in[7];
  const float* in_b   = (const float*)d_in[8];
  const float* out_w  = (const float*)d_in[9];
  const float* out_b  = (const float*)d_in[10];
  const float* ln2_g  = (const float*)d_in[11];
  const float* ln2_b  = (const float*)d_in[12];
  const float* fc1_w  = (const float*)d_in[13];
  const float* fc1_b  = (const float*)d_in[14];
  const float* fc2_w  = (const float*)d_in[15];
  const float* fc2_b  = (const float*)d_in[16];
  float* out = (float*)d_out;

  char* pws = (char*)d_ws;
  size_t off = 0;
  auto alloc = [&](size_t bytes) {
    void* r = pws + off; off = (off + bytes + 255) & ~(size_t)255; return r;
  };
  ushort_t* w_qkv = (ushort_t*)alloc((size_t)3 * E * E * 2);
  ushort_t* w_na  = (ushort_t*)alloc((size_t)E * E * 2);
  ushort_t* w_in  = (ushort_t*)alloc((size_t)3 * E * E * 2);
  ushort_t* w_fc1 = (ushort_t*)alloc((size_t)FDIM * E * 2);
  ushort_t* w_fc2 = (ushort_t*)alloc((size_t)E * FDIM * 2);
  ushort_t* xn1   = (ushort_t*)alloc((size_t)NTOK * E * 2);     // reused as xn2
  char*     bigR  = (char*)alloc((size_t)NTOK * FDIM * 2);      // phase-shared region
  ushort_t* qkvb  = (ushort_t*)bigR;                            // phase A: qkv
  ushort_t* natt  = (ushort_t*)(bigR + (size_t)NLOC * 3 * E * 2); // phase A: natten out
  ushort_t* kvg   = (ushort_t*)bigR;                            // phase B: fused K|V [NTOK][1024]
  ushort_t* hbuf  = (ushort_t*)bigR;                            // phase C: MLP hidden
  ushort_t* tmpk  = (ushort_t*)alloc((size_t)NTOK * E * 2);
  float*    sc    = (float*)alloc((size_t)BB * H * LP1 * 4);
  float*    qcls  = (float*)alloc(1024 * 4);
  float*    parts = (float*)alloc(9 * 16 * 64 * 4);
  float*    oc    = (float*)alloc(1024 * 4);
  float*    xcls  = (float*)alloc(1024 * 4);
  float*    xa    = (float*)alloc((size_t)NTOK * E * 4);
  ushort_t* xn2   = xn1;
  // split-K partial (fp32, NTOK x E) -- only if workspace allows
  size_t off_before_s0 = off;
  float*    s0    = (float*)alloc((size_t)NTOK * E * 4);
  const bool can_split = (off <= ws_size);
  if (!can_split) off = off_before_s0;

  // fused weight converts
  cvt_all<<<3840, 256, 0, stream>>>(
      qkv_w, w_qkv, 3 * E * E,
      na_w,  w_na,  E * E,
      in_w,  w_in,  3 * E * E,
      fc1_w, w_fc1, FDIM * E,
      fc2_w, w_fc2, E * FDIM);

  // LN1 (+ tmp_key cls rows)
  ln_fused1<<<NTOK, 256, 0, stream>>>(x, ln1_g, ln1_b, xn1, tmpk);
  // CLS query projection
  qcls_kernel<<<4, 256, 0, stream>>>(xn1, in_w, in_b, qcls);
  // QKV for local tokens (nx=64, ny=12)
  gemm_bt<128,0,0,0,1,0,0><<<64 * 12, 256, 0, stream>>>(
      xn1, w_qkv, qkv_b, nullptr, qkvb, nullptr, NLOC, 3 * E, E, E, 12, 1);
  // neighborhood attention (MFMA)
  natten_mfma<<<512, 256, 0, stream>>>(qkvb, natt);
  // output projection -> tmp_key rows (nx=64, ny=4)
  gemm_bt<128,0,0,0,0,1,0><<<64 * 4, 256, 0, stream>>>(
      natt, w_na, na_b, nullptr, tmpk, nullptr, NLOC, E, E, E, 4, 1);
  // fused global K+V projection (nx=65, ny=8)
  gemm_bt<128,0,0,0,0,0,0><<<65 * 8, 256, 0, stream>>>(
      tmpk, w_in + (size_t)E * E, in_b + E, nullptr, kvg, nullptr, NTOK, 1024, E, E, 8, 1);
  // CLS attention
  gscore_kernel<<<(BB * LP1 + 3) / 4, 256, 0, stream>>>(qcls, kvg, sc);
  gsoftmax_kernel<<<BB * H, 256, 0, stream>>>(sc);
  gpv_kernel<<<dim3(9, BB * H), 256, 0, stream>>>(sc, kvg, parts);
  gpv_reduce<<<4, 256, 0, stream>>>(parts, oc);
  xcls_kernel<<<4, 256, 0, stream>>>(oc, out_w, out_b, xcls);
  // residual + LN2
  resid_ln2<<<NTOK, 256, 0, stream>>>(x, tmpk, xcls, ln2_g, ln2_b, xa, xn2);
  // MLP fc1 (nx=65, ny=16)
  gemm_bt<128,1,0,0,0,0,0><<<65 * 16, 256, 0, stream>>>(
      xn2, w_fc1, fc1_b, nullptr, hbuf, nullptr, NTOK, FDIM, E, E, 16, 1);
  if (can_split) {
    // fc2 split-K=2 (nx=65, ny=4, nz=2): z=0 -> s0 (raw), z=1 -> out (raw); then reduce
    gemm_bt<128,0,0,0,0,0,1><<<65 * 4 * 2, 256, 0, stream>>>(
        hbuf, w_fc2, fc2_b, s0, (ushort_t*)out, nullptr, NTOK, E, FDIM, FDIM / 2, 4, 2);
    fc2_reduce<<<(NTOK * E / 4) / 256, 256, 0, stream>>>(out, s0, fc2_b, xa);
  } else {
    gemm_bt<128,0,1,1,0,0,0><<<65 * 4, 256, 0, stream>>>(
        hbuf, w_fc2, fc2_b, out, nullptr, xa, NTOK, E, FDIM, FDIM, 4, 1);
  }
}